// Round 5
// baseline (1306.389 us; speedup 1.0000x reference)
//
#include <hip/hip_runtime.h>
#include <hip/hip_fp16.h>

#define NN 50000
#define EE 800000
#define TT 1000000
#define QQ 1000000
#define GG 4096
#define HID 128
#define NH 8
#define DH 16
#define CAPC 96

__device__ __forceinline__ float eluf(float x){ return x > 0.f ? x : expm1f(x); }

// ---------------- count incident interactions per dst node (all 3 types, 1 launch) ----------------
__global__ void k_count3(const int* __restrict__ ei, const int* __restrict__ ti, const int* __restrict__ qi,
                         int* __restrict__ cnt){
  int i = blockIdx.x*blockDim.x + threadIdx.x;
  if (i < EE) atomicAdd(&cnt[ei[i]], 1);
  else if (i < EE+TT) atomicAdd(&cnt[NN + ti[i-EE]], 1);
  else if (i < EE+TT+QQ) atomicAdd(&cnt[2*NN + qi[i-EE-TT]], 1);
}

// ---------------- 3 scans (off+cur) + graph offsets, one launch (grid=4) ----------------
__global__ __launch_bounds__(1024) void k_scan4(const int* __restrict__ cnt,
    int* __restrict__ off_e, int* __restrict__ off_t, int* __restrict__ off_q,
    int* __restrict__ cur_e, int* __restrict__ cur_t, int* __restrict__ cur_q,
    const int* __restrict__ batch, int* __restrict__ goff){
  int b = blockIdx.x, t = threadIdx.x;
  if (b == 3){
    for (int g=t; g<=GG; g+=1024){
      int lo=0, hi=NN;
      while (lo<hi){ int mid=(lo+hi)>>1; if (batch[mid]<g) lo=mid+1; else hi=mid; }
      goff[g]=lo;
    }
    return;
  }
  __shared__ int part[1024];
  const int* c = cnt + b*NN;
  int* off = (b==0)?off_e:(b==1)?off_t:off_q;
  int* cur = (b==0)?cur_e:(b==1)?cur_t:cur_q;
  int chunk = (NN + 1023) >> 10;
  int s0 = t*chunk, s1 = min(NN, s0+chunk);
  int sum = 0;
  for (int i=s0;i<s1;i++) sum += c[i];
  part[t] = sum;
  __syncthreads();
  for (int d=1; d<1024; d<<=1){
    int v = (t>=d) ? part[t-d] : 0;
    __syncthreads();
    part[t] += v;
    __syncthreads();
  }
  int run = (t==0) ? 0 : part[t-1];
  for (int i=s0;i<s1;i++){ off[i]=run; cur[i]=run; run += c[i]; }
  if (t==0) off[NN] = part[1023];
}

// ---------------- fill CSR: packed (src,geom) int2 scatter + edge_attr permute ----------------
__global__ void k_fillgeom(const float* __restrict__ pos, const float* __restrict__ edge_attr,
    const int* __restrict__ ei, const int* __restrict__ ti, const int* __restrict__ qi,
    int* __restrict__ cur_e, int* __restrict__ cur_t, int* __restrict__ cur_q,
    int2* __restrict__ csg_e, int2* __restrict__ csg_t, int2* __restrict__ csg_q,
    float* __restrict__ eaP){
  int i = blockIdx.x*blockDim.x + threadIdx.x;
  if (i < EE){
    int dn = ei[i], sn = ei[EE+i];
    float dx = pos[dn*3+0]-pos[sn*3+0]+1e-8f;
    float dy = pos[dn*3+1]-pos[sn*3+1]+1e-8f;
    float dz = pos[dn*3+2]-pos[sn*3+2]+1e-8f;
    float d = sqrtf(dx*dx+dy*dy+dz*dz);
    int p = atomicAdd(&cur_e[dn], 1);
    csg_e[p] = make_int2(sn, __float_as_int(d));
    const float4* s = (const float4*)(edge_attr + (size_t)i*16);
    float4* dst4 = (float4*)(eaP + (size_t)p*16);
    dst4[0]=s[0]; dst4[1]=s[1]; dst4[2]=s[2]; dst4[3]=s[3];
  } else if (i < EE+TT){
    int m = i-EE;
    int a = ti[m], b = ti[TT+m], c = ti[2*TT+m];
    float ux = pos[a*3+0]-pos[b*3+0], uy = pos[a*3+1]-pos[b*3+1], uz = pos[a*3+2]-pos[b*3+2];
    float vx = pos[c*3+0]-pos[b*3+0], vy = pos[c*3+1]-pos[b*3+1], vz = pos[c*3+2]-pos[b*3+2];
    float num = ux*vx+uy*vy+uz*vz;
    float den = sqrtf(ux*ux+uy*uy+uz*uz)*sqrtf(vx*vx+vy*vy+vz*vz) + 1e-8f;
    int p = atomicAdd(&cur_t[a], 1);
    csg_t[p] = make_int2(c, __float_as_int(num/den));
  } else if (i < EE+TT+QQ){
    int m = i-EE-TT;
    int p0 = qi[m], p1 = qi[QQ+m], p2 = qi[2*QQ+m], p3 = qi[3*QQ+m];
    float b1x = pos[p1*3+0]-pos[p0*3+0], b1y = pos[p1*3+1]-pos[p0*3+1], b1z = pos[p1*3+2]-pos[p0*3+2];
    float b2x = pos[p2*3+0]-pos[p1*3+0], b2y = pos[p2*3+1]-pos[p1*3+1], b2z = pos[p2*3+2]-pos[p1*3+2];
    float b3x = pos[p3*3+0]-pos[p2*3+0], b3y = pos[p3*3+1]-pos[p2*3+1], b3z = pos[p3*3+2]-pos[p2*3+2];
    float n1x = b1y*b2z - b1z*b2y, n1y = b1z*b2x - b1x*b2z, n1z = b1x*b2y - b1y*b2x;
    float n2x = b2y*b3z - b2z*b3y, n2y = b2z*b3x - b2x*b3z, n2z = b2x*b3y - b2y*b3x;
    float num = n1x*n2x+n1y*n2y+n1z*n2z;
    float den = sqrtf(n1x*n1x+n1y*n1y+n1z*n1z)*sqrtf(n2x*n2x+n2y*n2y+n2z*n2z) + 1e-8f;
    int p = atomicAdd(&cur_q[p0], 1);
    csg_q[p] = make_int2(p3, __float_as_int(num/den));
  }
}

// ---------------- GEMM hl = A @ W  (A: [n,128], W: [128,128]); A rows wave-uniform ->
// scalar loads; W reads coalesced (L2-resident). Also writes fp16 mirror.
#define GR 16
__global__ __launch_bounds__(128) void k_gemm(const float* __restrict__ A, const float* __restrict__ W,
                                              float* __restrict__ B, __half* __restrict__ B16){
  int col = threadIdx.x;
  int r0 = blockIdx.x * GR;
  const float* Ab = A + (size_t)r0*HID;
  float acc[GR];
  #pragma unroll
  for (int r=0;r<GR;r++) acc[r]=0.f;
  #pragma unroll 4
  for (int k=0;k<HID;k++){
    float wv = W[k*HID+col];
    #pragma unroll
    for (int r=0;r<GR;r++) acc[r] = fmaf(Ab[r*HID+k], wv, acc[r]);
  }
  #pragma unroll
  for (int r=0;r<GR;r++){
    size_t oi = (size_t)(r0+r)*HID+col;
    B[oi] = acc[r];
    B16[oi] = __float2half(acc[r]);
  }
}

// ---------------- per-node attn projections (NN*8 threads) + CSR-ordered edge bias (EE threads) ----------------
__global__ void k_projbias(const float* __restrict__ hl,
    const float* __restrict__ ae, const float* __restrict__ at, const float* __restrict__ aq,
    const float* __restrict__ eaP, const float* __restrict__ Wel,
    float* __restrict__ qa_e, float* __restrict__ ka_e,
    float* __restrict__ qa_t, float* __restrict__ ka_t,
    float* __restrict__ qa_q, float* __restrict__ ka_q,
    float* __restrict__ biasP){
  int i = blockIdx.x*blockDim.x + threadIdx.x;
  if (i < NN*NH){
    int h = i & 7; int n = i >> 3;
    const float* v = hl + (size_t)n*HID + h*DH;
    float x[DH];
    #pragma unroll
    for (int d=0; d<DH; d++) x[d] = v[d];
    const float* Ae = ae + h*33; const float* At_ = at + h*33; const float* Aq = aq + h*33;
    float s0=0,s1=0,s2=0,s3=0,s4=0,s5=0;
    #pragma unroll
    for (int d=0; d<DH; d++){
      s0 = fmaf(x[d], Ae[d],      s0);  s1 = fmaf(x[d], Ae[DH+d],  s1);
      s2 = fmaf(x[d], At_[d],     s2);  s3 = fmaf(x[d], At_[DH+d], s3);
      s4 = fmaf(x[d], Aq[d],      s4);  s5 = fmaf(x[d], Aq[DH+d],  s5);
    }
    qa_e[i]=s0; ka_e[i]=s1; qa_t[i]=s2; ka_t[i]=s3; qa_q[i]=s4; ka_q[i]=s5;
  } else {
    int m = i - NN*NH;   // CSR position directly: read eaP + write biasP both sequential
    if (m < EE){
      float a[16];
      const float4* s4 = (const float4*)(eaP + (size_t)m*16);
      float4 v0=s4[0], v1=s4[1], v2=s4[2], v3=s4[3];
      a[0]=v0.x;a[1]=v0.y;a[2]=v0.z;a[3]=v0.w; a[4]=v1.x;a[5]=v1.y;a[6]=v1.z;a[7]=v1.w;
      a[8]=v2.x;a[9]=v2.y;a[10]=v2.z;a[11]=v2.w; a[12]=v3.x;a[13]=v3.y;a[14]=v3.z;a[15]=v3.w;
      size_t p = (size_t)m*NH;
      #pragma unroll
      for (int h=0;h<NH;h++){
        float s = 0.f;
        #pragma unroll
        for (int c=0;c<16;c++) s = fmaf(a[c], Wel[c*NH+h], s);
        biasP[p+h] = s;
      }
    }
  }
}

// ---------------- gather helper: 4 independent row-loads in flight per wave ----------------
__device__ __forceinline__ void gather_acc(const __half* __restrict__ hh16,
    const int* __restrict__ srcs, const float* __restrict__ es,
    int cnt, int w, int hg, int l, float& a0, float& a1){
  int m = w;
  for (; m+8 <= cnt; m += 8){
    int s0=srcs[m], s1=srcs[m+2], s2=srcs[m+4], s3=srcs[m+6];
    float e0=es[m*NH+hg], e1=es[(m+2)*NH+hg], e2=es[(m+4)*NH+hg], e3=es[(m+6)*NH+hg];
    float2 f0 = __half22float2(*(const __half2*)&hh16[(size_t)s0*HID + 2*l]);
    float2 f1 = __half22float2(*(const __half2*)&hh16[(size_t)s1*HID + 2*l]);
    float2 f2 = __half22float2(*(const __half2*)&hh16[(size_t)s2*HID + 2*l]);
    float2 f3 = __half22float2(*(const __half2*)&hh16[(size_t)s3*HID + 2*l]);
    a0 = fmaf(f0.x, e0, a0); a1 = fmaf(f0.y, e0, a1);
    a0 = fmaf(f1.x, e1, a0); a1 = fmaf(f1.y, e1, a1);
    a0 = fmaf(f2.x, e2, a0); a1 = fmaf(f2.y, e2, a1);
    a0 = fmaf(f3.x, e3, a0); a1 = fmaf(f3.y, e3, a1);
  }
  for (; m < cnt; m += 2){
    int s0 = srcs[m];
    float e0 = es[m*NH+hg];
    float2 f0 = __half22float2(*(const __half2*)&hh16[(size_t)s0*HID + 2*l]);
    a0 = fmaf(f0.x, e0, a0); a1 = fmaf(f0.y, e0, a1);
  }
}

// ---------------- fused 3-hop attention + residual + ELU, one block (128 thr) per node ----
__global__ __launch_bounds__(128) void k_hop3(
    const int* __restrict__ off_e, const int* __restrict__ off_t, const int* __restrict__ off_q,
    const int2* __restrict__ csg_e, const int2* __restrict__ csg_t, const int2* __restrict__ csg_q,
    const float* __restrict__ biasP,
    const float* __restrict__ qa_e, const float* __restrict__ ka_e,
    const float* __restrict__ qa_t, const float* __restrict__ ka_t,
    const float* __restrict__ qa_q, const float* __restrict__ ka_q,
    const float* __restrict__ ae, const float* __restrict__ at, const float* __restrict__ aq,
    const __half* __restrict__ hh16, const float* __restrict__ hlr, float* __restrict__ hout){
  __shared__ float sh_e[3][CAPC*NH];   // 9216 B (reused as reduction buffer at tail)
  __shared__ int   sh_src[3][CAPC];
  __shared__ float sh_geom[3][CAPC];
  __shared__ float sh_s[3*NH];
  __shared__ float sh_qa[3*NH];
  __shared__ float sh_coef[3*NH];
  int n = blockIdx.x, t = threadIdx.x;
  int w = t >> 6, l = t & 63;
  if (t < 24){
    int p = t>>3, h = t&7;
    const float* a  = (p==0)?ae:(p==1)?at:aq;
    const float* qa = (p==0)?qa_e:(p==1)?qa_t:qa_q;
    sh_coef[t] = a[h*33+32];
    sh_qa[t]   = qa[n*NH+h];
    sh_s[t]    = 0.f;
  }
  int st_e = off_e[n], de = off_e[n+1]-st_e;
  int st_t = off_t[n], dt = off_t[n+1]-st_t;
  int st_q = off_q[n], dq = off_q[n+1]-st_q;
  __syncthreads();
  float aE0=0,aE1=0,aT0=0,aT1=0,aQ0=0,aQ1=0;
  int h  = t & 7;        // head for logit items
  int hg = l >> 3;       // head for gathered dims (2l, 2l+1)
  int maxd = max(de, max(dt, dq));
  for (int base=0; base<maxd; base+=CAPC){
    int ce = min(CAPC, de-base); if (ce<0) ce=0;
    int ct = min(CAPC, dt-base); if (ct<0) ct=0;
    int cq = min(CAPC, dq-base); if (cq<0) cq=0;
    if (t < ce){ int2 v = csg_e[st_e+base+t]; sh_src[0][t]=v.x; sh_geom[0][t]=__int_as_float(v.y); }
    if (t < ct){ int2 v = csg_t[st_t+base+t]; sh_src[1][t]=v.x; sh_geom[1][t]=__int_as_float(v.y); }
    if (t < cq){ int2 v = csg_q[st_q+base+t]; sh_src[2][t]=v.x; sh_geom[2][t]=__int_as_float(v.y); }
    __syncthreads();
    // ---- logits for all 3 hops; private denominators (h fixed per thread) ----
    float dE=0.f, dT=0.f, dQ=0.f;
    for (int i=t; i<ce*NH; i+=128){
      int m = i>>3;
      float lg = sh_qa[h] + ka_e[sh_src[0][m]*NH+h] + sh_geom[0][m]*sh_coef[h]
               + biasP[(size_t)(st_e+base)*NH + i];
      lg = lg>=0.f ? lg : 0.2f*lg;
      float e = __expf(lg);
      sh_e[0][i] = e; dE += e;
    }
    for (int i=t; i<ct*NH; i+=128){
      int m = i>>3;
      float lg = sh_qa[8+h] + ka_t[sh_src[1][m]*NH+h] + sh_geom[1][m]*sh_coef[8+h];
      lg = lg>=0.f ? lg : 0.2f*lg;
      float e = __expf(lg);
      sh_e[1][i] = e; dT += e;
    }
    for (int i=t; i<cq*NH; i+=128){
      int m = i>>3;
      float lg = sh_qa[16+h] + ka_q[sh_src[2][m]*NH+h] + sh_geom[2][m]*sh_coef[16+h];
      lg = lg>=0.f ? lg : 0.2f*lg;
      float e = __expf(lg);
      sh_e[2][i] = e; dQ += e;
    }
    dE += __shfl_xor(dE, 8); dE += __shfl_xor(dE, 16); dE += __shfl_xor(dE, 32);
    dT += __shfl_xor(dT, 8); dT += __shfl_xor(dT, 16); dT += __shfl_xor(dT, 32);
    dQ += __shfl_xor(dQ, 8); dQ += __shfl_xor(dQ, 16); dQ += __shfl_xor(dQ, 32);
    if (l < 8){
      atomicAdd(&sh_s[l], dE);
      atomicAdd(&sh_s[8+l], dT);
      atomicAdd(&sh_s[16+l], dQ);
    }
    __syncthreads();
    gather_acc(hh16, sh_src[0], sh_e[0], ce, w, hg, l, aE0, aE1);
    gather_acc(hh16, sh_src[1], sh_e[1], ct, w, hg, l, aT0, aT1);
    gather_acc(hh16, sh_src[2], sh_e[2], cq, w, hg, l, aQ0, aQ1);
    __syncthreads();
  }
  // ---- tail: cross-wave combine (reuse sh_e as [3][2][128] buffer), divide, residual, ELU ----
  float* red = &sh_e[0][0];
  *(float2*)&red[(0*2+w)*128 + 2*l] = make_float2(aE0, aE1);
  *(float2*)&red[(1*2+w)*128 + 2*l] = make_float2(aT0, aT1);
  *(float2*)&red[(2*2+w)*128 + 2*l] = make_float2(aQ0, aQ1);
  __syncthreads();
  int ho = t >> 4;
  float outv = (red[t]       + red[128+t]) / (sh_s[ho]    + 1e-16f)
             + (red[256+t]   + red[384+t]) / (sh_s[8+ho]  + 1e-16f)
             + (red[512+t]   + red[640+t]) / (sh_s[16+ho] + 1e-16f);
  size_t oi = (size_t)n*HID + t;
  hout[oi] = eluf(hlr[oi] + outv);
}

// ---------------- pooling: sum + max per graph ----------------
__global__ __launch_bounds__(128) void k_pool(const float* __restrict__ h, const int* __restrict__ goff,
                                              float* __restrict__ gs, float* __restrict__ gmx){
  int g = blockIdx.x, t = threadIdx.x;
  int s = goff[g], e = goff[g+1];
  float sum = 0.f, mx = -INFINITY;
  for (int n=s; n<e; n++){
    float v = h[(size_t)n*HID+t];
    sum += v; mx = fmaxf(mx, v);
  }
  gs[(size_t)g*HID+t] = sum;
  gmx[(size_t)g*HID+t] = (s < e) ? mx : 0.f;
}

// ---------------- readout MLP: [257]->256->256->1, 8 graphs per block ----------------
#define GPB 8
#define MSTR 260
__global__ __launch_bounds__(256) void k_mlp(const float* __restrict__ gs, const float* __restrict__ gmx,
    const float* __restrict__ temps,
    const float* __restrict__ W1, const float* __restrict__ b1,
    const float* __restrict__ W2, const float* __restrict__ b2,
    const float* __restrict__ W3, const float* __restrict__ b3,
    float* __restrict__ out){
  __shared__ float mol[GPB][MSTR];
  __shared__ float hd[GPB][MSTR];
  int g0 = blockIdx.x*GPB, t = threadIdx.x;
  for (int i=t; i<GPB*HID; i+=256){
    int g=i>>7, d=i&127;
    mol[g][d]     = gs[(size_t)(g0+g)*HID+d];
    mol[g][128+d] = gmx[(size_t)(g0+g)*HID+d];
  }
  if (t < GPB){ mol[t][256]=temps[g0+t]; mol[t][257]=0.f; mol[t][258]=0.f; mol[t][259]=0.f; }
  __syncthreads();
  float acc[GPB];
  #pragma unroll
  for (int g=0;g<GPB;g++) acc[g]=b1[t];
  for (int k0=0;k0<256;k0+=4){
    float w0=W1[(size_t)(k0+0)*256+t], w1=W1[(size_t)(k0+1)*256+t];
    float w2=W1[(size_t)(k0+2)*256+t], w3=W1[(size_t)(k0+3)*256+t];
    #pragma unroll
    for (int g=0;g<GPB;g++){
      float4 m4 = *(const float4*)&mol[g][k0];
      acc[g] = fmaf(m4.x,w0, fmaf(m4.y,w1, fmaf(m4.z,w2, fmaf(m4.w,w3, acc[g]))));
    }
  }
  { float wl=W1[(size_t)256*256+t];
    #pragma unroll
    for (int g=0;g<GPB;g++) acc[g]=fmaf(mol[g][256],wl,acc[g]); }
  #pragma unroll
  for (int g=0;g<GPB;g++) hd[g][t]=eluf(acc[g]);
  __syncthreads();
  #pragma unroll
  for (int g=0;g<GPB;g++) acc[g]=b2[t];
  for (int k0=0;k0<256;k0+=4){
    float w0=W2[(size_t)(k0+0)*256+t], w1=W2[(size_t)(k0+1)*256+t];
    float w2=W2[(size_t)(k0+2)*256+t], w3=W2[(size_t)(k0+3)*256+t];
    #pragma unroll
    for (int g=0;g<GPB;g++){
      float4 h4 = *(const float4*)&hd[g][k0];
      acc[g] = fmaf(h4.x,w0, fmaf(h4.y,w1, fmaf(h4.z,w2, fmaf(h4.w,w3, acc[g]))));
    }
  }
  float w3v = W3[t];
  #pragma unroll
  for (int g=0;g<GPB;g++) mol[g][t] = eluf(acc[g])*w3v;   // mol reused as reduction buffer
  __syncthreads();
  int g = t >> 5, j = t & 31;
  float s = 0.f;
  for (int i=j; i<256; i+=32) s += mol[g][i];
  #pragma unroll
  for (int d=16; d>0; d>>=1) s += __shfl_down(s, d, 32);
  if (j == 0) out[g0+g] = s + b3[0];
}

extern "C" void kernel_launch(void* const* d_in, const int* in_sizes, int n_in,
                              void* d_out, int out_size, void* d_ws, size_t ws_size,
                              hipStream_t stream){
  const float* x         = (const float*)d_in[0];
  const float* pos       = (const float*)d_in[1];
  const float* edge_attr = (const float*)d_in[2];
  const float* temps     = (const float*)d_in[3];
  const int*   ei        = (const int*)d_in[4];
  const int*   ti        = (const int*)d_in[5];
  const int*   qi        = (const int*)d_in[6];
  const int*   batch     = (const int*)d_in[7];
  const float* W         = (const float*)d_in[8];
  const float* a_e       = (const float*)d_in[9];
  const float* a_t       = (const float*)d_in[10];
  const float* a_q       = (const float*)d_in[11];
  const float* We        = (const float*)d_in[12];
  const float* W1        = (const float*)d_in[13];
  const float* b1        = (const float*)d_in[14];
  const float* W2        = (const float*)d_in[15];
  const float* b2        = (const float*)d_in[16];
  const float* W3        = (const float*)d_in[17];
  const float* b3        = (const float*)d_in[18];
  float* out = (float*)d_out;

  char* base = (char*)d_ws; size_t woff = 0;
  auto alloc = [&](size_t bytes)->void*{
    void* p = base + woff;
    woff = (woff + bytes + 255) & ~(size_t)255;
    return p;
  };
  float*  hbuf   = (float*)alloc((size_t)NN*HID*4);
  float*  hl     = (float*)alloc((size_t)NN*HID*4);
  __half* hl16   = (__half*)alloc((size_t)NN*HID*2);
  float*  qa_e   = (float*)alloc((size_t)NN*NH*4);
  float*  ka_e   = (float*)alloc((size_t)NN*NH*4);
  float*  qa_t   = (float*)alloc((size_t)NN*NH*4);
  float*  ka_t   = (float*)alloc((size_t)NN*NH*4);
  float*  qa_q   = (float*)alloc((size_t)NN*NH*4);
  float*  ka_q   = (float*)alloc((size_t)NN*NH*4);
  int2*   csg_e  = (int2*)alloc((size_t)EE*8);
  int2*   csg_t  = (int2*)alloc((size_t)TT*8);
  int2*   csg_q  = (int2*)alloc((size_t)QQ*8);
  float*  eaP    = (float*)alloc((size_t)EE*16*4);
  float*  biasP  = (float*)alloc((size_t)EE*NH*4);
  float*  gs     = (float*)alloc((size_t)GG*HID*4);
  float*  gmx    = (float*)alloc((size_t)GG*HID*4);
  int*    cnt    = (int*)alloc((size_t)3*NN*4);
  int*    off_e  = (int*)alloc((size_t)(NN+1)*4);
  int*    off_t  = (int*)alloc((size_t)(NN+1)*4);
  int*    off_q  = (int*)alloc((size_t)(NN+1)*4);
  int*    cur_e  = (int*)alloc((size_t)NN*4);
  int*    cur_t  = (int*)alloc((size_t)NN*4);
  int*    cur_q  = (int*)alloc((size_t)NN*4);
  int*    goff   = (int*)alloc((size_t)(GG+1)*4);

  // ---- CSR build + geometry ----
  hipMemsetAsync(cnt, 0, (size_t)3*NN*4, stream);
  int tot = EE+TT+QQ;
  k_count3<<<(tot+255)/256,256,0,stream>>>(ei, ti, qi, cnt);
  k_scan4<<<4,1024,0,stream>>>(cnt, off_e, off_t, off_q, cur_e, cur_t, cur_q, batch, goff);
  k_fillgeom<<<(tot+255)/256,256,0,stream>>>(pos, edge_attr, ei, ti, qi, cur_e, cur_t, cur_q,
                                             csg_e, csg_t, csg_q, eaP);

  // ---- layers ----
  for (int l=0; l<3; l++){
    const float* hin = (l==0) ? x : hbuf;
    k_gemm<<<NN/GR,128,0,stream>>>(hin, W + (size_t)l*HID*HID, hl, hl16);
    k_projbias<<<(NN*NH+EE+255)/256,256,0,stream>>>(hl, a_e+l*264, a_t+l*264, a_q+l*264,
                                                    eaP, We + l*DH*NH,
                                                    qa_e, ka_e, qa_t, ka_t, qa_q, ka_q, biasP);
    k_hop3<<<NN,128,0,stream>>>(off_e, off_t, off_q, csg_e, csg_t, csg_q, biasP,
                                qa_e, ka_e, qa_t, ka_t, qa_q, ka_q,
                                a_e+l*264, a_t+l*264, a_q+l*264,
                                hl16, hl, hbuf);
  }

  // ---- readout ----
  k_pool<<<GG,128,0,stream>>>(hbuf, goff, gs, gmx);
  k_mlp<<<GG/GPB,256,0,stream>>>(gs, gmx, temps, W1, b1, W2, b2, W3, b3, out);
}

// Round 6
// 1227.858 us; speedup vs baseline: 1.0640x; 1.0640x over previous
//
#include <hip/hip_runtime.h>
#include <hip/hip_fp16.h>

#define NN 50000
#define EE 800000
#define TT 1000000
#define QQ 1000000
#define GG 4096
#define HID 128
#define NH 8
#define DH 16
#define CAPC 96

typedef unsigned int u32;
typedef unsigned int u32x4 __attribute__((ext_vector_type(4)));

__device__ __forceinline__ float eluf(float x){ return x > 0.f ? x : expm1f(x); }

// pack (src:16 | fp16(geom):16)  -- NN=50000 < 65536
__device__ __forceinline__ u32 pack_sg(int src, float g){
  return ((u32)src << 16) | (u32)__half_as_ushort(__float2half(g));
}

// ---------------- count incident interactions per dst node (all 3 types, 1 launch) ----------------
__global__ void k_count3(const int* __restrict__ ei, const int* __restrict__ ti, const int* __restrict__ qi,
                         int* __restrict__ cnt){
  int i = blockIdx.x*blockDim.x + threadIdx.x;
  if (i < EE) atomicAdd(&cnt[ei[i]], 1);
  else if (i < EE+TT) atomicAdd(&cnt[NN + ti[i-EE]], 1);
  else if (i < EE+TT+QQ) atomicAdd(&cnt[2*NN + qi[i-EE-TT]], 1);
}

// ---------------- 3 scans (off+cur) + graph offsets, one launch (grid=4) ----------------
__global__ __launch_bounds__(1024) void k_scan4(const int* __restrict__ cnt,
    int* __restrict__ off_e, int* __restrict__ off_t, int* __restrict__ off_q,
    int* __restrict__ cur_e, int* __restrict__ cur_t, int* __restrict__ cur_q,
    const int* __restrict__ batch, int* __restrict__ goff){
  int b = blockIdx.x, t = threadIdx.x;
  if (b == 3){
    for (int g=t; g<=GG; g+=1024){
      int lo=0, hi=NN;
      while (lo<hi){ int mid=(lo+hi)>>1; if (batch[mid]<g) lo=mid+1; else hi=mid; }
      goff[g]=lo;
    }
    return;
  }
  __shared__ int part[1024];
  const int* c = cnt + b*NN;
  int* off = (b==0)?off_e:(b==1)?off_t:off_q;
  int* cur = (b==0)?cur_e:(b==1)?cur_t:cur_q;
  int chunk = (NN + 1023) >> 10;
  int s0 = t*chunk, s1 = min(NN, s0+chunk);
  int sum = 0;
  for (int i=s0;i<s1;i++) sum += c[i];
  part[t] = sum;
  __syncthreads();
  for (int d=1; d<1024; d<<=1){
    int v = (t>=d) ? part[t-d] : 0;
    __syncthreads();
    part[t] += v;
    __syncthreads();
  }
  int run = (t==0) ? 0 : part[t-1];
  for (int i=s0;i<s1;i++){ off[i]=run; cur[i]=run; run += c[i]; }
  if (t==0) off[NN] = part[1023];
}

// ---------------- fill CSR: packed u32 (src|fp16 geom) scatter + fp16 edge_attr permute ----------------
__global__ void k_fillgeom(const float* __restrict__ pos, const float* __restrict__ edge_attr,
    const int* __restrict__ ei, const int* __restrict__ ti, const int* __restrict__ qi,
    int* __restrict__ cur_e, int* __restrict__ cur_t, int* __restrict__ cur_q,
    u32* __restrict__ csg_e, u32* __restrict__ csg_t, u32* __restrict__ csg_q,
    __half* __restrict__ eaP){
  int i = blockIdx.x*blockDim.x + threadIdx.x;
  if (i < EE){
    int dn = ei[i], sn = ei[EE+i];
    float dx = pos[dn*3+0]-pos[sn*3+0]+1e-8f;
    float dy = pos[dn*3+1]-pos[sn*3+1]+1e-8f;
    float dz = pos[dn*3+2]-pos[sn*3+2]+1e-8f;
    float d = sqrtf(dx*dx+dy*dy+dz*dz);
    int p = atomicAdd(&cur_e[dn], 1);
    __builtin_nontemporal_store(pack_sg(sn, d), &csg_e[p]);
    const float4* s = (const float4*)(edge_attr + (size_t)i*16);
    float4 v0=s[0], v1=s[1], v2=s[2], v3=s[3];
    __half2 h0=__floats2half2_rn(v0.x,v0.y), h1=__floats2half2_rn(v0.z,v0.w);
    __half2 h2=__floats2half2_rn(v1.x,v1.y), h3=__floats2half2_rn(v1.z,v1.w);
    __half2 h4=__floats2half2_rn(v2.x,v2.y), h5=__floats2half2_rn(v2.z,v2.w);
    __half2 h6=__floats2half2_rn(v3.x,v3.y), h7=__floats2half2_rn(v3.z,v3.w);
    u32x4 pk0, pk1;
    pk0[0]=*(u32*)&h0; pk0[1]=*(u32*)&h1; pk0[2]=*(u32*)&h2; pk0[3]=*(u32*)&h3;
    pk1[0]=*(u32*)&h4; pk1[1]=*(u32*)&h5; pk1[2]=*(u32*)&h6; pk1[3]=*(u32*)&h7;
    u32x4* dsts = (u32x4*)(eaP + (size_t)p*16);
    __builtin_nontemporal_store(pk0, &dsts[0]);
    __builtin_nontemporal_store(pk1, &dsts[1]);
  } else if (i < EE+TT){
    int m = i-EE;
    int a = ti[m], b = ti[TT+m], c = ti[2*TT+m];
    float ux = pos[a*3+0]-pos[b*3+0], uy = pos[a*3+1]-pos[b*3+1], uz = pos[a*3+2]-pos[b*3+2];
    float vx = pos[c*3+0]-pos[b*3+0], vy = pos[c*3+1]-pos[b*3+1], vz = pos[c*3+2]-pos[b*3+2];
    float num = ux*vx+uy*vy+uz*vz;
    float den = sqrtf(ux*ux+uy*uy+uz*uz)*sqrtf(vx*vx+vy*vy+vz*vz) + 1e-8f;
    int p = atomicAdd(&cur_t[a], 1);
    __builtin_nontemporal_store(pack_sg(c, num/den), &csg_t[p]);
  } else if (i < EE+TT+QQ){
    int m = i-EE-TT;
    int p0 = qi[m], p1 = qi[QQ+m], p2 = qi[2*QQ+m], p3 = qi[3*QQ+m];
    float b1x = pos[p1*3+0]-pos[p0*3+0], b1y = pos[p1*3+1]-pos[p0*3+1], b1z = pos[p1*3+2]-pos[p0*3+2];
    float b2x = pos[p2*3+0]-pos[p1*3+0], b2y = pos[p2*3+1]-pos[p1*3+1], b2z = pos[p2*3+2]-pos[p1*3+2];
    float b3x = pos[p3*3+0]-pos[p2*3+0], b3y = pos[p3*3+1]-pos[p2*3+1], b3z = pos[p3*3+2]-pos[p2*3+2];
    float n1x = b1y*b2z - b1z*b2y, n1y = b1z*b2x - b1x*b2z, n1z = b1x*b2y - b1y*b2x;
    float n2x = b2y*b3z - b2z*b3y, n2y = b2z*b3x - b2x*b3z, n2z = b2x*b3y - b2y*b3x;
    float num = n1x*n2x+n1y*n2y+n1z*n2z;
    float den = sqrtf(n1x*n1x+n1y*n1y+n1z*n1z)*sqrtf(n2x*n2x+n2y*n2y+n2z*n2z) + 1e-8f;
    int p = atomicAdd(&cur_q[p0], 1);
    __builtin_nontemporal_store(pack_sg(p3, num/den), &csg_q[p]);
  }
}

// ---------------- GEMM hl16 = fp16(A @ W)  (A: [n,128] fp32, W: [128,128]) ----------------
#define GR 16
__global__ __launch_bounds__(128) void k_gemm(const float* __restrict__ A, const float* __restrict__ W,
                                              __half* __restrict__ B16){
  int col = threadIdx.x;
  int r0 = blockIdx.x * GR;
  const float* Ab = A + (size_t)r0*HID;
  float acc[GR];
  #pragma unroll
  for (int r=0;r<GR;r++) acc[r]=0.f;
  #pragma unroll 4
  for (int k=0;k<HID;k++){
    float wv = W[k*HID+col];
    #pragma unroll
    for (int r=0;r<GR;r++) acc[r] = fmaf(Ab[r*HID+k], wv, acc[r]);
  }
  #pragma unroll
  for (int r=0;r<GR;r++) B16[(size_t)(r0+r)*HID+col] = __float2half(acc[r]);
}

// ---------------- per-node attn projections (NN*8 threads, fp16 in) + CSR-ordered edge bias (EE threads) ----------------
__global__ void k_projbias(const __half* __restrict__ hl16,
    const float* __restrict__ ae, const float* __restrict__ at, const float* __restrict__ aq,
    const __half* __restrict__ eaP, const float* __restrict__ Wel,
    float* __restrict__ qa_e, float* __restrict__ ka_e,
    float* __restrict__ qa_t, float* __restrict__ ka_t,
    float* __restrict__ qa_q, float* __restrict__ ka_q,
    __half* __restrict__ biasP){
  int i = blockIdx.x*blockDim.x + threadIdx.x;
  if (i < NN*NH){
    int h = i & 7; int n = i >> 3;
    const __half2* v2 = (const __half2*)(hl16 + (size_t)n*HID + h*DH);
    float x[DH];
    #pragma unroll
    for (int d2=0; d2<8; d2++){ float2 f = __half22float2(v2[d2]); x[2*d2]=f.x; x[2*d2+1]=f.y; }
    const float* Ae = ae + h*33; const float* At_ = at + h*33; const float* Aq = aq + h*33;
    float s0=0,s1=0,s2=0,s3=0,s4=0,s5=0;
    #pragma unroll
    for (int d=0; d<DH; d++){
      s0 = fmaf(x[d], Ae[d],      s0);  s1 = fmaf(x[d], Ae[DH+d],  s1);
      s2 = fmaf(x[d], At_[d],     s2);  s3 = fmaf(x[d], At_[DH+d], s3);
      s4 = fmaf(x[d], Aq[d],      s4);  s5 = fmaf(x[d], Aq[DH+d],  s5);
    }
    qa_e[i]=s0; ka_e[i]=s1; qa_t[i]=s2; ka_t[i]=s3; qa_q[i]=s4; ka_q[i]=s5;
  } else {
    int m = i - NN*NH;   // CSR position directly: eaP read + biasP write both sequential
    if (m < EE){
      const __half2* s2 = (const __half2*)(eaP + (size_t)m*16);
      float a[16];
      #pragma unroll
      for (int d2=0; d2<8; d2++){ float2 f = __half22float2(s2[d2]); a[2*d2]=f.x; a[2*d2+1]=f.y; }
      __half2* bp = (__half2*)(biasP + (size_t)m*NH);
      #pragma unroll
      for (int hp=0; hp<4; hp++){
        float sa = 0.f, sb = 0.f;
        #pragma unroll
        for (int c=0;c<16;c++){
          sa = fmaf(a[c], Wel[c*NH + 2*hp],     sa);
          sb = fmaf(a[c], Wel[c*NH + 2*hp + 1], sb);
        }
        bp[hp] = __floats2half2_rn(sa, sb);
      }
    }
  }
}

// ---------------- gather helper: 4 independent row-loads in flight per wave ----------------
__device__ __forceinline__ void gather_acc(const __half* __restrict__ hh16,
    const int* __restrict__ srcs, const float* __restrict__ es,
    int cnt, int w, int hg, int l, float& a0, float& a1){
  int m = w;
  for (; m+8 <= cnt; m += 8){
    int s0=srcs[m], s1=srcs[m+2], s2=srcs[m+4], s3=srcs[m+6];
    float e0=es[m*NH+hg], e1=es[(m+2)*NH+hg], e2=es[(m+4)*NH+hg], e3=es[(m+6)*NH+hg];
    float2 f0 = __half22float2(*(const __half2*)&hh16[(size_t)s0*HID + 2*l]);
    float2 f1 = __half22float2(*(const __half2*)&hh16[(size_t)s1*HID + 2*l]);
    float2 f2 = __half22float2(*(const __half2*)&hh16[(size_t)s2*HID + 2*l]);
    float2 f3 = __half22float2(*(const __half2*)&hh16[(size_t)s3*HID + 2*l]);
    a0 = fmaf(f0.x, e0, a0); a1 = fmaf(f0.y, e0, a1);
    a0 = fmaf(f1.x, e1, a0); a1 = fmaf(f1.y, e1, a1);
    a0 = fmaf(f2.x, e2, a0); a1 = fmaf(f2.y, e2, a1);
    a0 = fmaf(f3.x, e3, a0); a1 = fmaf(f3.y, e3, a1);
  }
  for (; m < cnt; m += 2){
    int s0 = srcs[m];
    float e0 = es[m*NH+hg];
    float2 f0 = __half22float2(*(const __half2*)&hh16[(size_t)s0*HID + 2*l]);
    a0 = fmaf(f0.x, e0, a0); a1 = fmaf(f0.y, e0, a1);
  }
}

// ---------------- fused 3-hop attention + residual + ELU, one block (128 thr) per node ----
__global__ __launch_bounds__(128) void k_hop3(
    const int* __restrict__ off_e, const int* __restrict__ off_t, const int* __restrict__ off_q,
    const u32* __restrict__ csg_e, const u32* __restrict__ csg_t, const u32* __restrict__ csg_q,
    const __half* __restrict__ biasP,
    const float* __restrict__ qa_e, const float* __restrict__ ka_e,
    const float* __restrict__ qa_t, const float* __restrict__ ka_t,
    const float* __restrict__ qa_q, const float* __restrict__ ka_q,
    const float* __restrict__ ae, const float* __restrict__ at, const float* __restrict__ aq,
    const __half* __restrict__ hh16, const __half* __restrict__ hlr16, float* __restrict__ hout){
  __shared__ float sh_e[3][CAPC*NH];   // 9216 B (reused as reduction buffer at tail)
  __shared__ int   sh_src[3][CAPC];
  __shared__ float sh_geom[3][CAPC];
  __shared__ float sh_s[3*NH];
  __shared__ float sh_qa[3*NH];
  __shared__ float sh_coef[3*NH];
  int n = blockIdx.x, t = threadIdx.x;
  int w = t >> 6, l = t & 63;
  if (t < 24){
    int p = t>>3, h = t&7;
    const float* a  = (p==0)?ae:(p==1)?at:aq;
    const float* qa = (p==0)?qa_e:(p==1)?qa_t:qa_q;
    sh_coef[t] = a[h*33+32];
    sh_qa[t]   = qa[n*NH+h];
    sh_s[t]    = 0.f;
  }
  int st_e = off_e[n], de = off_e[n+1]-st_e;
  int st_t = off_t[n], dt = off_t[n+1]-st_t;
  int st_q = off_q[n], dq = off_q[n+1]-st_q;
  __syncthreads();
  float aE0=0,aE1=0,aT0=0,aT1=0,aQ0=0,aQ1=0;
  int h  = t & 7;        // head for logit items
  int hg = l >> 3;       // head for gathered dims (2l, 2l+1)
  int maxd = max(de, max(dt, dq));
  for (int base=0; base<maxd; base+=CAPC){
    int ce = min(CAPC, de-base); if (ce<0) ce=0;
    int ct = min(CAPC, dt-base); if (ct<0) ct=0;
    int cq = min(CAPC, dq-base); if (cq<0) cq=0;
    if (t < ce){ u32 v = csg_e[st_e+base+t]; sh_src[0][t]=(int)(v>>16); sh_geom[0][t]=__half2float(__ushort_as_half((unsigned short)(v&0xFFFFu))); }
    if (t < ct){ u32 v = csg_t[st_t+base+t]; sh_src[1][t]=(int)(v>>16); sh_geom[1][t]=__half2float(__ushort_as_half((unsigned short)(v&0xFFFFu))); }
    if (t < cq){ u32 v = csg_q[st_q+base+t]; sh_src[2][t]=(int)(v>>16); sh_geom[2][t]=__half2float(__ushort_as_half((unsigned short)(v&0xFFFFu))); }
    __syncthreads();
    // ---- logits for all 3 hops; private denominators (h fixed per thread) ----
    float dE=0.f, dT=0.f, dQ=0.f;
    for (int i=t; i<ce*NH; i+=128){
      int m = i>>3;
      float lg = sh_qa[h] + ka_e[sh_src[0][m]*NH+h] + sh_geom[0][m]*sh_coef[h]
               + __half2float(biasP[(size_t)(st_e+base)*NH + i]);
      lg = lg>=0.f ? lg : 0.2f*lg;
      float e = __expf(lg);
      sh_e[0][i] = e; dE += e;
    }
    for (int i=t; i<ct*NH; i+=128){
      int m = i>>3;
      float lg = sh_qa[8+h] + ka_t[sh_src[1][m]*NH+h] + sh_geom[1][m]*sh_coef[8+h];
      lg = lg>=0.f ? lg : 0.2f*lg;
      float e = __expf(lg);
      sh_e[1][i] = e; dT += e;
    }
    for (int i=t; i<cq*NH; i+=128){
      int m = i>>3;
      float lg = sh_qa[16+h] + ka_q[sh_src[2][m]*NH+h] + sh_geom[2][m]*sh_coef[16+h];
      lg = lg>=0.f ? lg : 0.2f*lg;
      float e = __expf(lg);
      sh_e[2][i] = e; dQ += e;
    }
    dE += __shfl_xor(dE, 8); dE += __shfl_xor(dE, 16); dE += __shfl_xor(dE, 32);
    dT += __shfl_xor(dT, 8); dT += __shfl_xor(dT, 16); dT += __shfl_xor(dT, 32);
    dQ += __shfl_xor(dQ, 8); dQ += __shfl_xor(dQ, 16); dQ += __shfl_xor(dQ, 32);
    if (l < 8){
      atomicAdd(&sh_s[l], dE);
      atomicAdd(&sh_s[8+l], dT);
      atomicAdd(&sh_s[16+l], dQ);
    }
    __syncthreads();
    gather_acc(hh16, sh_src[0], sh_e[0], ce, w, hg, l, aE0, aE1);
    gather_acc(hh16, sh_src[1], sh_e[1], ct, w, hg, l, aT0, aT1);
    gather_acc(hh16, sh_src[2], sh_e[2], cq, w, hg, l, aQ0, aQ1);
    __syncthreads();
  }
  // ---- tail: cross-wave combine (reuse sh_e as [3][2][128] buffer), divide, residual, ELU ----
  float* red = &sh_e[0][0];
  *(float2*)&red[(0*2+w)*128 + 2*l] = make_float2(aE0, aE1);
  *(float2*)&red[(1*2+w)*128 + 2*l] = make_float2(aT0, aT1);
  *(float2*)&red[(2*2+w)*128 + 2*l] = make_float2(aQ0, aQ1);
  __syncthreads();
  int ho = t >> 4;
  float outv = (red[t]       + red[128+t]) / (sh_s[ho]    + 1e-16f)
             + (red[256+t]   + red[384+t]) / (sh_s[8+ho]  + 1e-16f)
             + (red[512+t]   + red[640+t]) / (sh_s[16+ho] + 1e-16f);
  size_t oi = (size_t)n*HID + t;
  hout[oi] = eluf(__half2float(hlr16[oi]) + outv);
}

// ---------------- pooling: sum + max per graph ----------------
__global__ __launch_bounds__(128) void k_pool(const float* __restrict__ h, const int* __restrict__ goff,
                                              float* __restrict__ gs, float* __restrict__ gmx){
  int g = blockIdx.x, t = threadIdx.x;
  int s = goff[g], e = goff[g+1];
  float sum = 0.f, mx = -INFINITY;
  for (int n=s; n<e; n++){
    float v = h[(size_t)n*HID+t];
    sum += v; mx = fmaxf(mx, v);
  }
  gs[(size_t)g*HID+t] = sum;
  gmx[(size_t)g*HID+t] = (s < e) ? mx : 0.f;
}

// ---------------- readout MLP: [257]->256->256->1, 8 graphs per block ----------------
#define GPB 8
#define MSTR 260
__global__ __launch_bounds__(256) void k_mlp(const float* __restrict__ gs, const float* __restrict__ gmx,
    const float* __restrict__ temps,
    const float* __restrict__ W1, const float* __restrict__ b1,
    const float* __restrict__ W2, const float* __restrict__ b2,
    const float* __restrict__ W3, const float* __restrict__ b3,
    float* __restrict__ out){
  __shared__ float mol[GPB][MSTR];
  __shared__ float hd[GPB][MSTR];
  int g0 = blockIdx.x*GPB, t = threadIdx.x;
  for (int i=t; i<GPB*HID; i+=256){
    int g=i>>7, d=i&127;
    mol[g][d]     = gs[(size_t)(g0+g)*HID+d];
    mol[g][128+d] = gmx[(size_t)(g0+g)*HID+d];
  }
  if (t < GPB){ mol[t][256]=temps[g0+t]; mol[t][257]=0.f; mol[t][258]=0.f; mol[t][259]=0.f; }
  __syncthreads();
  float acc[GPB];
  #pragma unroll
  for (int g=0;g<GPB;g++) acc[g]=b1[t];
  for (int k0=0;k0<256;k0+=4){
    float w0=W1[(size_t)(k0+0)*256+t], w1=W1[(size_t)(k0+1)*256+t];
    float w2=W1[(size_t)(k0+2)*256+t], w3=W1[(size_t)(k0+3)*256+t];
    #pragma unroll
    for (int g=0;g<GPB;g++){
      float4 m4 = *(const float4*)&mol[g][k0];
      acc[g] = fmaf(m4.x,w0, fmaf(m4.y,w1, fmaf(m4.z,w2, fmaf(m4.w,w3, acc[g]))));
    }
  }
  { float wl=W1[(size_t)256*256+t];
    #pragma unroll
    for (int g=0;g<GPB;g++) acc[g]=fmaf(mol[g][256],wl,acc[g]); }
  #pragma unroll
  for (int g=0;g<GPB;g++) hd[g][t]=eluf(acc[g]);
  __syncthreads();
  #pragma unroll
  for (int g=0;g<GPB;g++) acc[g]=b2[t];
  for (int k0=0;k0<256;k0+=4){
    float w0=W2[(size_t)(k0+0)*256+t], w1=W2[(size_t)(k0+1)*256+t];
    float w2=W2[(size_t)(k0+2)*256+t], w3=W2[(size_t)(k0+3)*256+t];
    #pragma unroll
    for (int g=0;g<GPB;g++){
      float4 h4 = *(const float4*)&hd[g][k0];
      acc[g] = fmaf(h4.x,w0, fmaf(h4.y,w1, fmaf(h4.z,w2, fmaf(h4.w,w3, acc[g]))));
    }
  }
  float w3v = W3[t];
  #pragma unroll
  for (int g=0;g<GPB;g++) mol[g][t] = eluf(acc[g])*w3v;   // mol reused as reduction buffer
  __syncthreads();
  int g = t >> 5, j = t & 31;
  float s = 0.f;
  for (int i=j; i<256; i+=32) s += mol[g][i];
  #pragma unroll
  for (int d=16; d>0; d>>=1) s += __shfl_down(s, d, 32);
  if (j == 0) out[g0+g] = s + b3[0];
}

extern "C" void kernel_launch(void* const* d_in, const int* in_sizes, int n_in,
                              void* d_out, int out_size, void* d_ws, size_t ws_size,
                              hipStream_t stream){
  const float* x         = (const float*)d_in[0];
  const float* pos       = (const float*)d_in[1];
  const float* edge_attr = (const float*)d_in[2];
  const float* temps     = (const float*)d_in[3];
  const int*   ei        = (const int*)d_in[4];
  const int*   ti        = (const int*)d_in[5];
  const int*   qi        = (const int*)d_in[6];
  const int*   batch     = (const int*)d_in[7];
  const float* W         = (const float*)d_in[8];
  const float* a_e       = (const float*)d_in[9];
  const float* a_t       = (const float*)d_in[10];
  const float* a_q       = (const float*)d_in[11];
  const float* We        = (const float*)d_in[12];
  const float* W1        = (const float*)d_in[13];
  const float* b1        = (const float*)d_in[14];
  const float* W2        = (const float*)d_in[15];
  const float* b2        = (const float*)d_in[16];
  const float* W3        = (const float*)d_in[17];
  const float* b3        = (const float*)d_in[18];
  float* out = (float*)d_out;

  char* base = (char*)d_ws; size_t woff = 0;
  auto alloc = [&](size_t bytes)->void*{
    void* p = base + woff;
    woff = (woff + bytes + 255) & ~(size_t)255;
    return p;
  };
  float*  hbuf   = (float*)alloc((size_t)NN*HID*4);
  __half* hl16   = (__half*)alloc((size_t)NN*HID*2);
  float*  qa_e   = (float*)alloc((size_t)NN*NH*4);
  float*  ka_e   = (float*)alloc((size_t)NN*NH*4);
  float*  qa_t   = (float*)alloc((size_t)NN*NH*4);
  float*  ka_t   = (float*)alloc((size_t)NN*NH*4);
  float*  qa_q   = (float*)alloc((size_t)NN*NH*4);
  float*  ka_q   = (float*)alloc((size_t)NN*NH*4);
  u32*    csg_e  = (u32*)alloc((size_t)EE*4);
  u32*    csg_t  = (u32*)alloc((size_t)TT*4);
  u32*    csg_q  = (u32*)alloc((size_t)QQ*4);
  __half* eaP    = (__half*)alloc((size_t)EE*16*2);
  __half* biasP  = (__half*)alloc((size_t)EE*NH*2);
  float*  gs     = (float*)alloc((size_t)GG*HID*4);
  float*  gmx    = (float*)alloc((size_t)GG*HID*4);
  int*    cnt    = (int*)alloc((size_t)3*NN*4);
  int*    off_e  = (int*)alloc((size_t)(NN+1)*4);
  int*    off_t  = (int*)alloc((size_t)(NN+1)*4);
  int*    off_q  = (int*)alloc((size_t)(NN+1)*4);
  int*    cur_e  = (int*)alloc((size_t)NN*4);
  int*    cur_t  = (int*)alloc((size_t)NN*4);
  int*    cur_q  = (int*)alloc((size_t)NN*4);
  int*    goff   = (int*)alloc((size_t)(GG+1)*4);

  // ---- CSR build + geometry ----
  hipMemsetAsync(cnt, 0, (size_t)3*NN*4, stream);
  int tot = EE+TT+QQ;
  k_count3<<<(tot+255)/256,256,0,stream>>>(ei, ti, qi, cnt);
  k_scan4<<<4,1024,0,stream>>>(cnt, off_e, off_t, off_q, cur_e, cur_t, cur_q, batch, goff);
  k_fillgeom<<<(tot+255)/256,256,0,stream>>>(pos, edge_attr, ei, ti, qi, cur_e, cur_t, cur_q,
                                             csg_e, csg_t, csg_q, eaP);

  // ---- layers ----
  for (int l=0; l<3; l++){
    const float* hin = (l==0) ? x : hbuf;
    k_gemm<<<NN/GR,128,0,stream>>>(hin, W + (size_t)l*HID*HID, hl16);
    k_projbias<<<(NN*NH+EE+255)/256,256,0,stream>>>(hl16, a_e+l*264, a_t+l*264, a_q+l*264,
                                                    eaP, We + l*DH*NH,
                                                    qa_e, ka_e, qa_t, ka_t, qa_q, ka_q, biasP);
    k_hop3<<<NN,128,0,stream>>>(off_e, off_t, off_q, csg_e, csg_t, csg_q, biasP,
                                qa_e, ka_e, qa_t, ka_t, qa_q, ka_q,
                                a_e+l*264, a_t+l*264, a_q+l*264,
                                hl16, hl16, hbuf);
  }

  // ---- readout ----
  k_pool<<<GG,128,0,stream>>>(hbuf, goff, gs, gmx);
  k_mlp<<<GG/GPB,256,0,stream>>>(gs, gmx, temps, W1, b1, W2, b2, W3, b3, out);
}

// Round 7
// 1188.094 us; speedup vs baseline: 1.0996x; 1.0335x over previous
//
#include <hip/hip_runtime.h>
#include <hip/hip_fp16.h>

#define NN 50000
#define EE 800000
#define TT 1000000
#define QQ 1000000
#define GG 4096
#define HID 128
#define NH 8
#define DH 16
#define CAPC 96

#define TILE 2048
#define KPT 8
#define NB 196            // ceil(NN/256) buckets per type
#define NBG 392           // T buckets + Q buckets

typedef unsigned int u32;
typedef unsigned int u32x4 __attribute__((ext_vector_type(4)));

__device__ __forceinline__ float eluf(float x){ return x > 0.f ? x : expm1f(x); }

// pack (src:16 | fp16(geom):16)  -- NN=50000 < 65536
__device__ __forceinline__ u32 pack_sg(int src, float g){
  return ((u32)src << 16) | (u32)__half_as_ushort(__float2half(g));
}

// ---------------- count incident interactions per dst node (all 3 types, 1 launch) ----------------
__global__ void k_count3(const int* __restrict__ ei, const int* __restrict__ ti, const int* __restrict__ qi,
                         int* __restrict__ cnt){
  int i = blockIdx.x*blockDim.x + threadIdx.x;
  if (i < EE) atomicAdd(&cnt[ei[i]], 1);
  else if (i < EE+TT) atomicAdd(&cnt[NN + ti[i-EE]], 1);
  else if (i < EE+TT+QQ) atomicAdd(&cnt[2*NN + qi[i-EE-TT]], 1);
}

// ---------------- 3 scans (off+cur) + graph offsets, one launch (grid=4) ----------------
__global__ __launch_bounds__(1024) void k_scan4(const int* __restrict__ cnt,
    int* __restrict__ off_e, int* __restrict__ off_t, int* __restrict__ off_q,
    int* __restrict__ cur_e, int* __restrict__ cur_t, int* __restrict__ cur_q,
    const int* __restrict__ batch, int* __restrict__ goff){
  int b = blockIdx.x, t = threadIdx.x;
  if (b == 3){
    for (int g=t; g<=GG; g+=1024){
      int lo=0, hi=NN;
      while (lo<hi){ int mid=(lo+hi)>>1; if (batch[mid]<g) lo=mid+1; else hi=mid; }
      goff[g]=lo;
    }
    return;
  }
  __shared__ int part[1024];
  const int* c = cnt + b*NN;
  int* off = (b==0)?off_e:(b==1)?off_t:off_q;
  int* cur = (b==0)?cur_e:(b==1)?cur_t:cur_q;
  int chunk = (NN + 1023) >> 10;
  int s0 = t*chunk, s1 = min(NN, s0+chunk);
  int sum = 0;
  for (int i=s0;i<s1;i++) sum += c[i];
  part[t] = sum;
  __syncthreads();
  for (int d=1; d<1024; d<<=1){
    int v = (t>=d) ? part[t-d] : 0;
    __syncthreads();
    part[t] += v;
    __syncthreads();
  }
  int run = (t==0) ? 0 : part[t-1];
  for (int i=s0;i<s1;i++){ off[i]=run; cur[i]=run; run += c[i]; }
  if (t==0) off[NN] = part[1023];
}

// ---------------- E edges: one 64B record per edge = {sg, pad, bias_l0[8], bias_l1[8], bias_l2[8]} ----------------
__global__ void k_fillE(const float* __restrict__ pos, const float* __restrict__ edge_attr,
    const int* __restrict__ ei, const float* __restrict__ We,  // [3][16][8]
    int* __restrict__ cur_e, u32* __restrict__ eRec){          // eRec: 16 u32 per edge
  int i = blockIdx.x*blockDim.x + threadIdx.x;
  if (i >= EE) return;
  int dn = ei[i], sn = ei[EE+i];
  float dx = pos[dn*3+0]-pos[sn*3+0]+1e-8f;
  float dy = pos[dn*3+1]-pos[sn*3+1]+1e-8f;
  float dz = pos[dn*3+2]-pos[sn*3+2]+1e-8f;
  float d = sqrtf(dx*dx+dy*dy+dz*dz);
  int p = atomicAdd(&cur_e[dn], 1);
  // load edge_attr row (fp32, 64B)
  const float4* s = (const float4*)(edge_attr + (size_t)i*16);
  float4 v0=s[0], v1=s[1], v2=s[2], v3=s[3];
  float a[16] = {v0.x,v0.y,v0.z,v0.w, v1.x,v1.y,v1.z,v1.w,
                 v2.x,v2.y,v2.z,v2.w, v3.x,v3.y,v3.z,v3.w};
  u32x4 r[4];
  r[0][0] = pack_sg(sn, d); r[0][1]=0; r[0][2]=0; r[0][3]=0;
  #pragma unroll
  for (int l=0; l<3; l++){
    const float* Wel = We + l*DH*NH;
    #pragma unroll
    for (int hp=0; hp<4; hp++){
      float sa=0.f, sb=0.f;
      #pragma unroll
      for (int c=0;c<16;c++){
        sa = fmaf(a[c], Wel[c*NH + 2*hp],     sa);
        sb = fmaf(a[c], Wel[c*NH + 2*hp + 1], sb);
      }
      __half2 hh = __floats2half2_rn(sa, sb);
      r[1+l][hp] = *(u32*)&hh;
    }
  }
  u32x4* dst4 = (u32x4*)(eRec + (size_t)p*16);
  dst4[0]=r[0]; dst4[1]=r[1]; dst4[2]=r[2]; dst4[3]=r[3];
}

// ---------------- T/Q stage A: tile counting-sort by dst-bucket, append runs to staging ----------------
__global__ __launch_bounds__(256) void k_fillTQ_A(const float* __restrict__ pos,
    const int* __restrict__ ti, const int* __restrict__ qi,
    const int* __restrict__ off_t, const int* __restrict__ off_q,
    u32* __restrict__ gcur, uint2* __restrict__ stg){
  __shared__ u32 s_sg[TILE];
  __shared__ u32 s_dw[TILE];
  __shared__ u32 s_cnt[NBG];
  __shared__ u32 s_scan[512];
  __shared__ u32 s_gb[NBG];
  int t = threadIdx.x;
  size_t tile0 = (size_t)blockIdx.x * TILE;
  for (int i=t;i<NBG;i+=256) s_cnt[i]=0;
  __syncthreads();
  u32 my_sg[KPT], my_dw[KPT], my_rank[KPT]; int my_bg[KPT];
  #pragma unroll
  for (int k=0;k<KPT;k++){
    size_t idx = tile0 + (size_t)k*256 + t;
    my_bg[k] = -1;
    if (idx < (size_t)TT+QQ){
      int dst, src; float g;
      int typeq = (idx >= (size_t)TT);
      if (!typeq){
        int m = (int)idx;
        int ia=ti[m], jb=ti[TT+m], kc=ti[2*TT+m];
        float ux=pos[ia*3+0]-pos[jb*3+0], uy=pos[ia*3+1]-pos[jb*3+1], uz=pos[ia*3+2]-pos[jb*3+2];
        float vx=pos[kc*3+0]-pos[jb*3+0], vy=pos[kc*3+1]-pos[jb*3+1], vz=pos[kc*3+2]-pos[jb*3+2];
        float num = ux*vx+uy*vy+uz*vz;
        float den = sqrtf(ux*ux+uy*uy+uz*uz)*sqrtf(vx*vx+vy*vy+vz*vz) + 1e-8f;
        g = num/den; dst = ia; src = kc;
      } else {
        int m = (int)(idx - TT);
        int p0=qi[m], p1=qi[QQ+m], p2=qi[2*QQ+m], p3=qi[3*QQ+m];
        float b1x=pos[p1*3+0]-pos[p0*3+0], b1y=pos[p1*3+1]-pos[p0*3+1], b1z=pos[p1*3+2]-pos[p0*3+2];
        float b2x=pos[p2*3+0]-pos[p1*3+0], b2y=pos[p2*3+1]-pos[p1*3+1], b2z=pos[p2*3+2]-pos[p1*3+2];
        float b3x=pos[p3*3+0]-pos[p2*3+0], b3y=pos[p3*3+1]-pos[p2*3+1], b3z=pos[p3*3+2]-pos[p2*3+2];
        float n1x=b1y*b2z-b1z*b2y, n1y=b1z*b2x-b1x*b2z, n1z=b1x*b2y-b1y*b2x;
        float n2x=b2y*b3z-b2z*b3y, n2y=b2z*b3x-b2x*b3z, n2z=b2x*b3y-b2y*b3x;
        float num = n1x*n2x+n1y*n2y+n1z*n2z;
        float den = sqrtf(n1x*n1x+n1y*n1y+n1z*n1z)*sqrtf(n2x*n2x+n2y*n2y+n2z*n2z) + 1e-8f;
        g = num/den; dst = p0; src = p3;
      }
      int bg = (typeq?NB:0) + (dst>>8);
      my_sg[k] = pack_sg(src, g);
      my_dw[k] = (u32)dst | ((u32)typeq<<20);
      my_bg[k] = bg;
      my_rank[k] = atomicAdd(&s_cnt[bg], 1u);
    }
  }
  __syncthreads();
  // inclusive scan of s_cnt (padded to 512) into s_scan
  int i0=t, i1=t+256;
  s_scan[i0] = (i0<NBG)? s_cnt[i0] : 0u;
  s_scan[i1] = (i1<NBG)? s_cnt[i1] : 0u;
  __syncthreads();
  for (int d=1; d<512; d<<=1){
    u32 a0 = (i0>=d)? s_scan[i0-d] : 0u;
    u32 a1 = (i1>=d)? s_scan[i1-d] : 0u;
    __syncthreads();
    s_scan[i0]+=a0; s_scan[i1]+=a1;
    __syncthreads();
  }
  u32 total = s_scan[NBG-1];
  // place records bucket-major in LDS
  #pragma unroll
  for (int k=0;k<KPT;k++){
    if (my_bg[k]>=0){
      u32 slot = s_scan[my_bg[k]] - s_cnt[my_bg[k]] + my_rank[k];
      s_sg[slot]=my_sg[k]; s_dw[slot]=my_dw[k];
    }
  }
  // reserve global runs per bucket
  for (int i=t;i<NBG;i+=256)
    s_gb[i] = s_cnt[i] ? atomicAdd(&gcur[i], s_cnt[i]) : 0u;
  __syncthreads();
  // flush runs (contiguous per bucket)
  for (u32 j=t; j<total; j+=256){
    u32 dw = s_dw[j];
    int typeq = (dw>>20)&1;
    int dst = dw & 0xFFFFF;
    int bg = (typeq?NB:0) + (dst>>8);
    u32 rank = j - (s_scan[bg]-s_cnt[bg]);
    int w0 = (typeq? bg-NB : bg)*256;
    size_t sbase = typeq ? (size_t)TT + (size_t)off_q[w0] : (size_t)off_t[w0];
    stg[sbase + s_gb[bg] + rank] = make_uint2(s_sg[j], dw);
  }
}

// ---------------- T/Q stage B: per-bucket windowed placement into final CSR order ----------------
__global__ __launch_bounds__(256) void k_fillTQ_B(const uint2* __restrict__ stg,
    const int* __restrict__ off_t, const int* __restrict__ off_q,
    u32* __restrict__ csg_t, u32* __restrict__ csg_q){
  __shared__ int curL[256];
  int b = blockIdx.x, t = threadIdx.x;
  int typeq = (b>=NB);
  int bl = typeq? b-NB : b;
  const int* off = typeq? off_q : off_t;
  u32* csg = typeq? csg_q : csg_t;
  int w0 = bl*256, w1 = min(w0+256, NN);
  int s0 = off[w0], s1 = off[w1];
  for (int i=t; i<w1-w0; i+=256) curL[i] = off[w0+i];
  __syncthreads();
  size_t sb = (typeq? (size_t)TT : 0) + (size_t)s0;
  int cnt = s1 - s0;
  for (int i=t; i<cnt; i+=256){
    uint2 r = stg[sb+i];
    int dst = r.y & 0xFFFFF;
    int p = atomicAdd(&curL[dst-w0], 1);
    csg[p] = r.x;
  }
}

// ---------------- GEMM hl16 = fp16(A @ W)  (A: [n,128] fp32, W: [128,128]) ----------------
#define GR 16
__global__ __launch_bounds__(128) void k_gemm(const float* __restrict__ A, const float* __restrict__ W,
                                              __half* __restrict__ B16){
  int col = threadIdx.x;
  int r0 = blockIdx.x * GR;
  const float* Ab = A + (size_t)r0*HID;
  float acc[GR];
  #pragma unroll
  for (int r=0;r<GR;r++) acc[r]=0.f;
  #pragma unroll 4
  for (int k=0;k<HID;k++){
    float wv = W[k*HID+col];
    #pragma unroll
    for (int r=0;r<GR;r++) acc[r] = fmaf(Ab[r*HID+k], wv, acc[r]);
  }
  #pragma unroll
  for (int r=0;r<GR;r++) B16[(size_t)(r0+r)*HID+col] = __float2half(acc[r]);
}

// ---------------- per-node attn projections (qa/ka for 3 hop types) ----------------
__global__ void k_proj(const __half* __restrict__ hl16,
    const float* __restrict__ ae, const float* __restrict__ at, const float* __restrict__ aq,
    float* __restrict__ qa_e, float* __restrict__ ka_e,
    float* __restrict__ qa_t, float* __restrict__ ka_t,
    float* __restrict__ qa_q, float* __restrict__ ka_q){
  int i = blockIdx.x*blockDim.x + threadIdx.x;
  if (i >= NN*NH) return;
  int h = i & 7; int n = i >> 3;
  const __half2* v2 = (const __half2*)(hl16 + (size_t)n*HID + h*DH);
  float x[DH];
  #pragma unroll
  for (int d2=0; d2<8; d2++){ float2 f = __half22float2(v2[d2]); x[2*d2]=f.x; x[2*d2+1]=f.y; }
  const float* Ae = ae + h*33; const float* At_ = at + h*33; const float* Aq = aq + h*33;
  float s0=0,s1=0,s2=0,s3=0,s4=0,s5=0;
  #pragma unroll
  for (int d=0; d<DH; d++){
    s0 = fmaf(x[d], Ae[d],      s0);  s1 = fmaf(x[d], Ae[DH+d],  s1);
    s2 = fmaf(x[d], At_[d],     s2);  s3 = fmaf(x[d], At_[DH+d], s3);
    s4 = fmaf(x[d], Aq[d],      s4);  s5 = fmaf(x[d], Aq[DH+d],  s5);
  }
  qa_e[i]=s0; ka_e[i]=s1; qa_t[i]=s2; ka_t[i]=s3; qa_q[i]=s4; ka_q[i]=s5;
}

// ---------------- gather helper: 4 independent row-loads in flight per wave ----------------
__device__ __forceinline__ void gather_acc(const __half* __restrict__ hh16,
    const int* __restrict__ srcs, const float* __restrict__ es,
    int cnt, int w, int hg, int l, float& a0, float& a1){
  int m = w;
  for (; m+8 <= cnt; m += 8){
    int s0=srcs[m], s1=srcs[m+2], s2=srcs[m+4], s3=srcs[m+6];
    float e0=es[m*NH+hg], e1=es[(m+2)*NH+hg], e2=es[(m+4)*NH+hg], e3=es[(m+6)*NH+hg];
    float2 f0 = __half22float2(*(const __half2*)&hh16[(size_t)s0*HID + 2*l]);
    float2 f1 = __half22float2(*(const __half2*)&hh16[(size_t)s1*HID + 2*l]);
    float2 f2 = __half22float2(*(const __half2*)&hh16[(size_t)s2*HID + 2*l]);
    float2 f3 = __half22float2(*(const __half2*)&hh16[(size_t)s3*HID + 2*l]);
    a0 = fmaf(f0.x, e0, a0); a1 = fmaf(f0.y, e0, a1);
    a0 = fmaf(f1.x, e1, a0); a1 = fmaf(f1.y, e1, a1);
    a0 = fmaf(f2.x, e2, a0); a1 = fmaf(f2.y, e2, a1);
    a0 = fmaf(f3.x, e3, a0); a1 = fmaf(f3.y, e3, a1);
  }
  for (; m < cnt; m += 2){
    int s0 = srcs[m];
    float e0 = es[m*NH+hg];
    float2 f0 = __half22float2(*(const __half2*)&hh16[(size_t)s0*HID + 2*l]);
    a0 = fmaf(f0.x, e0, a0); a1 = fmaf(f0.y, e0, a1);
  }
}

// ---------------- fused 3-hop attention + residual + ELU, one block (128 thr) per node ----
__global__ __launch_bounds__(128) void k_hop3(
    const int* __restrict__ off_e, const int* __restrict__ off_t, const int* __restrict__ off_q,
    const u32* __restrict__ eRec,
    const u32* __restrict__ csg_t, const u32* __restrict__ csg_q,
    const float* __restrict__ qa_e, const float* __restrict__ ka_e,
    const float* __restrict__ qa_t, const float* __restrict__ ka_t,
    const float* __restrict__ qa_q, const float* __restrict__ ka_q,
    const float* __restrict__ ae, const float* __restrict__ at, const float* __restrict__ aq,
    const __half* __restrict__ hh16, const __half* __restrict__ hlr16, float* __restrict__ hout,
    int L){
  __shared__ float sh_e[3][CAPC*NH];   // 9216 B (reused as reduction buffer at tail)
  __shared__ int   sh_src[3][CAPC];
  __shared__ float sh_geom[3][CAPC];
  __shared__ float sh_s[3*NH];
  __shared__ float sh_qa[3*NH];
  __shared__ float sh_coef[3*NH];
  int n = blockIdx.x, t = threadIdx.x;
  int w = t >> 6, l = t & 63;
  if (t < 24){
    int p = t>>3, h = t&7;
    const float* a  = (p==0)?ae:(p==1)?at:aq;
    const float* qa = (p==0)?qa_e:(p==1)?qa_t:qa_q;
    sh_coef[t] = a[h*33+32];
    sh_qa[t]   = qa[n*NH+h];
    sh_s[t]    = 0.f;
  }
  int st_e = off_e[n], de = off_e[n+1]-st_e;
  int st_t = off_t[n], dt = off_t[n+1]-st_t;
  int st_q = off_q[n], dq = off_q[n+1]-st_q;
  __syncthreads();
  float aE0=0,aE1=0,aT0=0,aT1=0,aQ0=0,aQ1=0;
  int h  = t & 7;        // head for logit items
  int hg = l >> 3;       // head for gathered dims (2l, 2l+1)
  const __half* eRecH = (const __half*)eRec;
  int maxd = max(de, max(dt, dq));
  for (int base=0; base<maxd; base+=CAPC){
    int ce = min(CAPC, de-base); if (ce<0) ce=0;
    int ct = min(CAPC, dt-base); if (ct<0) ct=0;
    int cq = min(CAPC, dq-base); if (cq<0) cq=0;
    if (t < ce){ u32 v = eRec[(size_t)(st_e+base+t)*16]; sh_src[0][t]=(int)(v>>16); sh_geom[0][t]=__half2float(__ushort_as_half((unsigned short)(v&0xFFFFu))); }
    if (t < ct){ u32 v = csg_t[st_t+base+t]; sh_src[1][t]=(int)(v>>16); sh_geom[1][t]=__half2float(__ushort_as_half((unsigned short)(v&0xFFFFu))); }
    if (t < cq){ u32 v = csg_q[st_q+base+t]; sh_src[2][t]=(int)(v>>16); sh_geom[2][t]=__half2float(__ushort_as_half((unsigned short)(v&0xFFFFu))); }
    __syncthreads();
    // ---- logits for all 3 hops; private denominators (h fixed per thread) ----
    float dE=0.f, dT=0.f, dQ=0.f;
    for (int i=t; i<ce*NH; i+=128){
      int m = i>>3;
      float lg = sh_qa[h] + ka_e[sh_src[0][m]*NH+h] + sh_geom[0][m]*sh_coef[h]
               + __half2float(eRecH[(size_t)(st_e+base+m)*32 + 8 + 8*L + h]);
      lg = lg>=0.f ? lg : 0.2f*lg;
      float e = __expf(lg);
      sh_e[0][i] = e; dE += e;
    }
    for (int i=t; i<ct*NH; i+=128){
      int m = i>>3;
      float lg = sh_qa[8+h] + ka_t[sh_src[1][m]*NH+h] + sh_geom[1][m]*sh_coef[8+h];
      lg = lg>=0.f ? lg : 0.2f*lg;
      float e = __expf(lg);
      sh_e[1][i] = e; dT += e;
    }
    for (int i=t; i<cq*NH; i+=128){
      int m = i>>3;
      float lg = sh_qa[16+h] + ka_q[sh_src[2][m]*NH+h] + sh_geom[2][m]*sh_coef[16+h];
      lg = lg>=0.f ? lg : 0.2f*lg;
      float e = __expf(lg);
      sh_e[2][i] = e; dQ += e;
    }
    dE += __shfl_xor(dE, 8); dE += __shfl_xor(dE, 16); dE += __shfl_xor(dE, 32);
    dT += __shfl_xor(dT, 8); dT += __shfl_xor(dT, 16); dT += __shfl_xor(dT, 32);
    dQ += __shfl_xor(dQ, 8); dQ += __shfl_xor(dQ, 16); dQ += __shfl_xor(dQ, 32);
    if (l < 8){
      atomicAdd(&sh_s[l], dE);
      atomicAdd(&sh_s[8+l], dT);
      atomicAdd(&sh_s[16+l], dQ);
    }
    __syncthreads();
    gather_acc(hh16, sh_src[0], sh_e[0], ce, w, hg, l, aE0, aE1);
    gather_acc(hh16, sh_src[1], sh_e[1], ct, w, hg, l, aT0, aT1);
    gather_acc(hh16, sh_src[2], sh_e[2], cq, w, hg, l, aQ0, aQ1);
    __syncthreads();
  }
  // ---- tail: cross-wave combine (reuse sh_e as [3][2][128] buffer), divide, residual, ELU ----
  float* red = &sh_e[0][0];
  *(float2*)&red[(0*2+w)*128 + 2*l] = make_float2(aE0, aE1);
  *(float2*)&red[(1*2+w)*128 + 2*l] = make_float2(aT0, aT1);
  *(float2*)&red[(2*2+w)*128 + 2*l] = make_float2(aQ0, aQ1);
  __syncthreads();
  int ho = t >> 4;
  float outv = (red[t]       + red[128+t]) / (sh_s[ho]    + 1e-16f)
             + (red[256+t]   + red[384+t]) / (sh_s[8+ho]  + 1e-16f)
             + (red[512+t]   + red[640+t]) / (sh_s[16+ho] + 1e-16f);
  size_t oi = (size_t)n*HID + t;
  hout[oi] = eluf(__half2float(hlr16[oi]) + outv);
}

// ---------------- pooling: sum + max per graph ----------------
__global__ __launch_bounds__(128) void k_pool(const float* __restrict__ h, const int* __restrict__ goff,
                                              float* __restrict__ gs, float* __restrict__ gmx){
  int g = blockIdx.x, t = threadIdx.x;
  int s = goff[g], e = goff[g+1];
  float sum = 0.f, mx = -INFINITY;
  for (int n=s; n<e; n++){
    float v = h[(size_t)n*HID+t];
    sum += v; mx = fmaxf(mx, v);
  }
  gs[(size_t)g*HID+t] = sum;
  gmx[(size_t)g*HID+t] = (s < e) ? mx : 0.f;
}

// ---------------- readout MLP: [257]->256->256->1, 8 graphs per block ----------------
#define GPB 8
#define MSTR 260
__global__ __launch_bounds__(256) void k_mlp(const float* __restrict__ gs, const float* __restrict__ gmx,
    const float* __restrict__ temps,
    const float* __restrict__ W1, const float* __restrict__ b1,
    const float* __restrict__ W2, const float* __restrict__ b2,
    const float* __restrict__ W3, const float* __restrict__ b3,
    float* __restrict__ out){
  __shared__ float mol[GPB][MSTR];
  __shared__ float hd[GPB][MSTR];
  int g0 = blockIdx.x*GPB, t = threadIdx.x;
  for (int i=t; i<GPB*HID; i+=256){
    int g=i>>7, d=i&127;
    mol[g][d]     = gs[(size_t)(g0+g)*HID+d];
    mol[g][128+d] = gmx[(size_t)(g0+g)*HID+d];
  }
  if (t < GPB){ mol[t][256]=temps[g0+t]; mol[t][257]=0.f; mol[t][258]=0.f; mol[t][259]=0.f; }
  __syncthreads();
  float acc[GPB];
  #pragma unroll
  for (int g=0;g<GPB;g++) acc[g]=b1[t];
  for (int k0=0;k0<256;k0+=4){
    float w0=W1[(size_t)(k0+0)*256+t], w1=W1[(size_t)(k0+1)*256+t];
    float w2=W1[(size_t)(k0+2)*256+t], w3=W1[(size_t)(k0+3)*256+t];
    #pragma unroll
    for (int g=0;g<GPB;g++){
      float4 m4 = *(const float4*)&mol[g][k0];
      acc[g] = fmaf(m4.x,w0, fmaf(m4.y,w1, fmaf(m4.z,w2, fmaf(m4.w,w3, acc[g]))));
    }
  }
  { float wl=W1[(size_t)256*256+t];
    #pragma unroll
    for (int g=0;g<GPB;g++) acc[g]=fmaf(mol[g][256],wl,acc[g]); }
  #pragma unroll
  for (int g=0;g<GPB;g++) hd[g][t]=eluf(acc[g]);
  __syncthreads();
  #pragma unroll
  for (int g=0;g<GPB;g++) acc[g]=b2[t];
  for (int k0=0;k0<256;k0+=4){
    float w0=W2[(size_t)(k0+0)*256+t], w1=W2[(size_t)(k0+1)*256+t];
    float w2=W2[(size_t)(k0+2)*256+t], w3=W2[(size_t)(k0+3)*256+t];
    #pragma unroll
    for (int g=0;g<GPB;g++){
      float4 h4 = *(const float4*)&hd[g][k0];
      acc[g] = fmaf(h4.x,w0, fmaf(h4.y,w1, fmaf(h4.z,w2, fmaf(h4.w,w3, acc[g]))));
    }
  }
  float w3v = W3[t];
  #pragma unroll
  for (int g=0;g<GPB;g++) mol[g][t] = eluf(acc[g])*w3v;   // mol reused as reduction buffer
  __syncthreads();
  int g = t >> 5, j = t & 31;
  float s = 0.f;
  for (int i=j; i<256; i+=32) s += mol[g][i];
  #pragma unroll
  for (int d=16; d>0; d>>=1) s += __shfl_down(s, d, 32);
  if (j == 0) out[g0+g] = s + b3[0];
}

extern "C" void kernel_launch(void* const* d_in, const int* in_sizes, int n_in,
                              void* d_out, int out_size, void* d_ws, size_t ws_size,
                              hipStream_t stream){
  const float* x         = (const float*)d_in[0];
  const float* pos       = (const float*)d_in[1];
  const float* edge_attr = (const float*)d_in[2];
  const float* temps     = (const float*)d_in[3];
  const int*   ei        = (const int*)d_in[4];
  const int*   ti        = (const int*)d_in[5];
  const int*   qi        = (const int*)d_in[6];
  const int*   batch     = (const int*)d_in[7];
  const float* W         = (const float*)d_in[8];
  const float* a_e       = (const float*)d_in[9];
  const float* a_t       = (const float*)d_in[10];
  const float* a_q       = (const float*)d_in[11];
  const float* We        = (const float*)d_in[12];
  const float* W1        = (const float*)d_in[13];
  const float* b1        = (const float*)d_in[14];
  const float* W2        = (const float*)d_in[15];
  const float* b2        = (const float*)d_in[16];
  const float* W3        = (const float*)d_in[17];
  const float* b3        = (const float*)d_in[18];
  float* out = (float*)d_out;

  char* base = (char*)d_ws; size_t woff = 0;
  auto alloc = [&](size_t bytes)->void*{
    void* p = base + woff;
    woff = (woff + bytes + 255) & ~(size_t)255;
    return p;
  };
  float*  hbuf   = (float*)alloc((size_t)NN*HID*4);
  __half* hl16   = (__half*)alloc((size_t)NN*HID*2);
  float*  qa_e   = (float*)alloc((size_t)NN*NH*4);
  float*  ka_e   = (float*)alloc((size_t)NN*NH*4);
  float*  qa_t   = (float*)alloc((size_t)NN*NH*4);
  float*  ka_t   = (float*)alloc((size_t)NN*NH*4);
  float*  qa_q   = (float*)alloc((size_t)NN*NH*4);
  float*  ka_q   = (float*)alloc((size_t)NN*NH*4);
  u32*    eRec   = (u32*)alloc((size_t)EE*64);        // 64B per E edge
  u32*    csg_t  = (u32*)alloc((size_t)TT*4);
  u32*    csg_q  = (u32*)alloc((size_t)QQ*4);
  uint2*  stg    = (uint2*)alloc((size_t)(TT+QQ)*8);  // T/Q staging
  float*  gs     = (float*)alloc((size_t)GG*HID*4);
  float*  gmx    = (float*)alloc((size_t)GG*HID*4);
  int*    cnt    = (int*)alloc((size_t)3*NN*4);
  u32*    gcur   = (u32*)alloc((size_t)NBG*4);
  int*    off_e  = (int*)alloc((size_t)(NN+1)*4);
  int*    off_t  = (int*)alloc((size_t)(NN+1)*4);
  int*    off_q  = (int*)alloc((size_t)(NN+1)*4);
  int*    cur_e  = (int*)alloc((size_t)NN*4);
  int*    cur_t  = (int*)alloc((size_t)NN*4);
  int*    cur_q  = (int*)alloc((size_t)NN*4);
  int*    goff   = (int*)alloc((size_t)(GG+1)*4);

  // ---- CSR build + geometry ----
  hipMemsetAsync(cnt, 0, (size_t)3*NN*4, stream);
  hipMemsetAsync(gcur, 0, (size_t)NBG*4, stream);
  int tot = EE+TT+QQ;
  k_count3<<<(tot+255)/256,256,0,stream>>>(ei, ti, qi, cnt);
  k_scan4<<<4,1024,0,stream>>>(cnt, off_e, off_t, off_q, cur_e, cur_t, cur_q, batch, goff);
  k_fillE<<<(EE+255)/256,256,0,stream>>>(pos, edge_attr, ei, We, cur_e, eRec);
  k_fillTQ_A<<<(TT+QQ+TILE-1)/TILE,256,0,stream>>>(pos, ti, qi, off_t, off_q, gcur, stg);
  k_fillTQ_B<<<NBG,256,0,stream>>>(stg, off_t, off_q, csg_t, csg_q);

  // ---- layers ----
  for (int l=0; l<3; l++){
    const float* hin = (l==0) ? x : hbuf;
    k_gemm<<<NN/GR,128,0,stream>>>(hin, W + (size_t)l*HID*HID, hl16);
    k_proj<<<(NN*NH+255)/256,256,0,stream>>>(hl16, a_e+l*264, a_t+l*264, a_q+l*264,
                                             qa_e, ka_e, qa_t, ka_t, qa_q, ka_q);
    k_hop3<<<NN,128,0,stream>>>(off_e, off_t, off_q, eRec, csg_t, csg_q,
                                qa_e, ka_e, qa_t, ka_t, qa_q, ka_q,
                                a_e+l*264, a_t+l*264, a_q+l*264,
                                hl16, hl16, hbuf, l);
  }

  // ---- readout ----
  k_pool<<<GG,128,0,stream>>>(hbuf, goff, gs, gmx);
  k_mlp<<<GG/GPB,256,0,stream>>>(gs, gmx, temps, W1, b1, W2, b2, W3, b3, out);
}

// Round 9
// 1184.435 us; speedup vs baseline: 1.1030x; 1.0031x over previous
//
#include <hip/hip_runtime.h>
#include <hip/hip_fp16.h>

#define NN 50000
#define EE 800000
#define TT 1000000
#define QQ 1000000
#define GG 4096
#define HID 128
#define NH 8
#define DH 16
#define CAP 64

#define TILE 2048
#define KPT 8
#define NB 196            // ceil(NN/256) buckets per type
#define NBG 392           // T buckets + Q buckets

typedef unsigned int u32;
typedef unsigned int u32x4 __attribute__((ext_vector_type(4)));

__device__ __forceinline__ float eluf(float x){ return x > 0.f ? x : expm1f(x); }

// pack (src:16 | fp16(geom):16)  -- NN=50000 < 65536
__device__ __forceinline__ u32 pack_sg(int src, float g){
  return ((u32)src << 16) | (u32)__half_as_ushort(__float2half(g));
}

// ---------------- count incident interactions per dst node (all 3 types, 1 launch) ----------------
__global__ void k_count3(const int* __restrict__ ei, const int* __restrict__ ti, const int* __restrict__ qi,
                         int* __restrict__ cnt){
  int i = blockIdx.x*blockDim.x + threadIdx.x;
  if (i < EE) atomicAdd(&cnt[ei[i]], 1);
  else if (i < EE+TT) atomicAdd(&cnt[NN + ti[i-EE]], 1);
  else if (i < EE+TT+QQ) atomicAdd(&cnt[2*NN + qi[i-EE-TT]], 1);
}

// ---------------- 3 scans (off+cur) + graph offsets, one launch (grid=4) ----------------
__global__ __launch_bounds__(1024) void k_scan4(const int* __restrict__ cnt,
    int* __restrict__ off_e, int* __restrict__ off_t, int* __restrict__ off_q,
    int* __restrict__ cur_e, int* __restrict__ cur_t, int* __restrict__ cur_q,
    const int* __restrict__ batch, int* __restrict__ goff){
  int b = blockIdx.x, t = threadIdx.x;
  if (b == 3){
    for (int g=t; g<=GG; g+=1024){
      int lo=0, hi=NN;
      while (lo<hi){ int mid=(lo+hi)>>1; if (batch[mid]<g) lo=mid+1; else hi=mid; }
      goff[g]=lo;
    }
    return;
  }
  __shared__ int part[1024];
  const int* c = cnt + b*NN;
  int* off = (b==0)?off_e:(b==1)?off_t:off_q;
  int* cur = (b==0)?cur_e:(b==1)?cur_t:cur_q;
  int chunk = (NN + 1023) >> 10;
  int s0 = t*chunk, s1 = min(NN, s0+chunk);
  int sum = 0;
  for (int i=s0;i<s1;i++) sum += c[i];
  part[t] = sum;
  __syncthreads();
  for (int d=1; d<1024; d<<=1){
    int v = (t>=d) ? part[t-d] : 0;
    __syncthreads();
    part[t] += v;
    __syncthreads();
  }
  int run = (t==0) ? 0 : part[t-1];
  for (int i=s0;i<s1;i++){ off[i]=run; cur[i]=run; run += c[i]; }
  if (t==0) off[NN] = part[1023];
}

// ---------------- E edges: one 64B record per edge = {sg, pad, bias_l0[8], bias_l1[8], bias_l2[8]} ----------------
__global__ void k_fillE(const float* __restrict__ pos, const float* __restrict__ edge_attr,
    const int* __restrict__ ei, const float* __restrict__ We,  // [3][16][8]
    int* __restrict__ cur_e, u32* __restrict__ eRec){          // eRec: 16 u32 per edge
  int i = blockIdx.x*blockDim.x + threadIdx.x;
  if (i >= EE) return;
  int dn = ei[i], sn = ei[EE+i];
  float dx = pos[dn*3+0]-pos[sn*3+0]+1e-8f;
  float dy = pos[dn*3+1]-pos[sn*3+1]+1e-8f;
  float dz = pos[dn*3+2]-pos[sn*3+2]+1e-8f;
  float d = sqrtf(dx*dx+dy*dy+dz*dz);
  int p = atomicAdd(&cur_e[dn], 1);
  const float4* s = (const float4*)(edge_attr + (size_t)i*16);
  float4 v0=s[0], v1=s[1], v2=s[2], v3=s[3];
  float a[16] = {v0.x,v0.y,v0.z,v0.w, v1.x,v1.y,v1.z,v1.w,
                 v2.x,v2.y,v2.z,v2.w, v3.x,v3.y,v3.z,v3.w};
  u32x4 r[4];
  r[0][0] = pack_sg(sn, d); r[0][1]=0; r[0][2]=0; r[0][3]=0;
  #pragma unroll
  for (int l=0; l<3; l++){
    const float* Wel = We + l*DH*NH;
    #pragma unroll
    for (int hp=0; hp<4; hp++){
      float sa=0.f, sb=0.f;
      #pragma unroll
      for (int c=0;c<16;c++){
        sa = fmaf(a[c], Wel[c*NH + 2*hp],     sa);
        sb = fmaf(a[c], Wel[c*NH + 2*hp + 1], sb);
      }
      __half2 hh = __floats2half2_rn(sa, sb);
      r[1+l][hp] = *(u32*)&hh;
    }
  }
  u32x4* dst4 = (u32x4*)(eRec + (size_t)p*16);
  dst4[0]=r[0]; dst4[1]=r[1]; dst4[2]=r[2]; dst4[3]=r[3];
}

// ---------------- T/Q stage A: tile counting-sort by dst-bucket, append runs to staging ----------------
__global__ __launch_bounds__(256) void k_fillTQ_A(const float* __restrict__ pos,
    const int* __restrict__ ti, const int* __restrict__ qi,
    const int* __restrict__ off_t, const int* __restrict__ off_q,
    u32* __restrict__ gcur, uint2* __restrict__ stg){
  __shared__ u32 s_sg[TILE];
  __shared__ u32 s_dw[TILE];
  __shared__ u32 s_cnt[NBG];
  __shared__ u32 s_scan[512];
  __shared__ u32 s_gb[NBG];
  int t = threadIdx.x;
  size_t tile0 = (size_t)blockIdx.x * TILE;
  for (int i=t;i<NBG;i+=256) s_cnt[i]=0;
  __syncthreads();
  u32 my_sg[KPT], my_dw[KPT], my_rank[KPT]; int my_bg[KPT];
  #pragma unroll
  for (int k=0;k<KPT;k++){
    size_t idx = tile0 + (size_t)k*256 + t;
    my_bg[k] = -1;
    if (idx < (size_t)TT+QQ){
      int dst, src; float g;
      int typeq = (idx >= (size_t)TT);
      if (!typeq){
        int m = (int)idx;
        int ia=ti[m], jb=ti[TT+m], kc=ti[2*TT+m];
        float ux=pos[ia*3+0]-pos[jb*3+0], uy=pos[ia*3+1]-pos[jb*3+1], uz=pos[ia*3+2]-pos[jb*3+2];
        float vx=pos[kc*3+0]-pos[jb*3+0], vy=pos[kc*3+1]-pos[jb*3+1], vz=pos[kc*3+2]-pos[jb*3+2];
        float num = ux*vx+uy*vy+uz*vz;
        float den = sqrtf(ux*ux+uy*uy+uz*uz)*sqrtf(vx*vx+vy*vy+vz*vz) + 1e-8f;
        g = num/den; dst = ia; src = kc;
      } else {
        int m = (int)(idx - TT);
        int p0=qi[m], p1=qi[QQ+m], p2=qi[2*QQ+m], p3=qi[3*QQ+m];
        float b1x=pos[p1*3+0]-pos[p0*3+0], b1y=pos[p1*3+1]-pos[p0*3+1], b1z=pos[p1*3+2]-pos[p0*3+2];
        float b2x=pos[p2*3+0]-pos[p1*3+0], b2y=pos[p2*3+1]-pos[p1*3+1], b2z=pos[p2*3+2]-pos[p1*3+2];
        float b3x=pos[p3*3+0]-pos[p2*3+0], b3y=pos[p3*3+1]-pos[p2*3+1], b3z=pos[p3*3+2]-pos[p2*3+2];
        float n1x=b1y*b2z-b1z*b2y, n1y=b1z*b2x-b1x*b2z, n1z=b1x*b2y-b1y*b2x;
        float n2x=b2y*b3z-b2z*b3y, n2y=b2z*b3x-b2x*b3z, n2z=b2x*b3y-b2y*b3x;
        float num = n1x*n2x+n1y*n2y+n1z*n2z;
        float den = sqrtf(n1x*n1x+n1y*n1y+n1z*n1z)*sqrtf(n2x*n2x+n2y*n2y+n2z*n2z) + 1e-8f;
        g = num/den; dst = p0; src = p3;
      }
      int bg = (typeq?NB:0) + (dst>>8);
      my_sg[k] = pack_sg(src, g);
      my_dw[k] = (u32)dst | ((u32)typeq<<20);
      my_bg[k] = bg;
      my_rank[k] = atomicAdd(&s_cnt[bg], 1u);
    }
  }
  __syncthreads();
  int i0=t, i1=t+256;
  s_scan[i0] = (i0<NBG)? s_cnt[i0] : 0u;
  s_scan[i1] = (i1<NBG)? s_cnt[i1] : 0u;
  __syncthreads();
  for (int d=1; d<512; d<<=1){
    u32 a0 = (i0>=d)? s_scan[i0-d] : 0u;
    u32 a1 = (i1>=d)? s_scan[i1-d] : 0u;
    __syncthreads();
    s_scan[i0]+=a0; s_scan[i1]+=a1;
    __syncthreads();
  }
  u32 total = s_scan[NBG-1];
  #pragma unroll
  for (int k=0;k<KPT;k++){
    if (my_bg[k]>=0){
      u32 slot = s_scan[my_bg[k]] - s_cnt[my_bg[k]] + my_rank[k];
      s_sg[slot]=my_sg[k]; s_dw[slot]=my_dw[k];
    }
  }
  for (int i=t;i<NBG;i+=256)
    s_gb[i] = s_cnt[i] ? atomicAdd(&gcur[i], s_cnt[i]) : 0u;
  __syncthreads();
  for (u32 j=t; j<total; j+=256){
    u32 dw = s_dw[j];
    int typeq = (dw>>20)&1;
    int dst = dw & 0xFFFFF;
    int bg = (typeq?NB:0) + (dst>>8);
    u32 rank = j - (s_scan[bg]-s_cnt[bg]);
    int w0 = (typeq? bg-NB : bg)*256;
    size_t sbase = typeq ? (size_t)TT + (size_t)off_q[w0] : (size_t)off_t[w0];
    stg[sbase + s_gb[bg] + rank] = make_uint2(s_sg[j], dw);
  }
}

// ---------------- T/Q stage B: per-bucket windowed placement into final CSR order ----------------
__global__ __launch_bounds__(256) void k_fillTQ_B(const uint2* __restrict__ stg,
    const int* __restrict__ off_t, const int* __restrict__ off_q,
    u32* __restrict__ csg_t, u32* __restrict__ csg_q){
  __shared__ int curL[256];
  int b = blockIdx.x, t = threadIdx.x;
  int typeq = (b>=NB);
  int bl = typeq? b-NB : b;
  const int* off = typeq? off_q : off_t;
  u32* csg = typeq? csg_q : csg_t;
  int w0 = bl*256, w1 = min(w0+256, NN);
  int s0 = off[w0], s1 = off[w1];
  for (int i=t; i<w1-w0; i+=256) curL[i] = off[w0+i];
  __syncthreads();
  size_t sb = (typeq? (size_t)TT : 0) + (size_t)s0;
  int cnt = s1 - s0;
  for (int i=t; i<cnt; i+=256){
    uint2 r = stg[sb+i];
    int dst = r.y & 0xFFFFF;
    int p = atomicAdd(&curL[dst-w0], 1);
    csg[p] = r.x;
  }
}

// ---------------- GEMM hl16 = fp16(A @ W)  (A: [n,128] fp32, W: [128,128]) ----------------
#define GR 16
__global__ __launch_bounds__(128) void k_gemm(const float* __restrict__ A, const float* __restrict__ W,
                                              __half* __restrict__ B16){
  int col = threadIdx.x;
  int r0 = blockIdx.x * GR;
  const float* Ab = A + (size_t)r0*HID;
  float acc[GR];
  #pragma unroll
  for (int r=0;r<GR;r++) acc[r]=0.f;
  #pragma unroll 4
  for (int k=0;k<HID;k++){
    float wv = W[k*HID+col];
    #pragma unroll
    for (int r=0;r<GR;r++) acc[r] = fmaf(Ab[r*HID+k], wv, acc[r]);
  }
  #pragma unroll
  for (int r=0;r<GR;r++) B16[(size_t)(r0+r)*HID+col] = __float2half(acc[r]);
}

// ---------------- per-node attn projections (qa/ka for 3 hop types) ----------------
__global__ void k_proj(const __half* __restrict__ hl16,
    const float* __restrict__ ae, const float* __restrict__ at, const float* __restrict__ aq,
    float* __restrict__ qa_e, float* __restrict__ ka_e,
    float* __restrict__ qa_t, float* __restrict__ ka_t,
    float* __restrict__ qa_q, float* __restrict__ ka_q){
  int i = blockIdx.x*blockDim.x + threadIdx.x;
  if (i >= NN*NH) return;
  int h = i & 7; int n = i >> 3;
  const __half2* v2 = (const __half2*)(hl16 + (size_t)n*HID + h*DH);
  float x[DH];
  #pragma unroll
  for (int d2=0; d2<8; d2++){ float2 f = __half22float2(v2[d2]); x[2*d2]=f.x; x[2*d2+1]=f.y; }
  const float* Ae = ae + h*33; const float* At_ = at + h*33; const float* Aq = aq + h*33;
  float s0=0,s1=0,s2=0,s3=0,s4=0,s5=0;
  #pragma unroll
  for (int d=0; d<DH; d++){
    s0 = fmaf(x[d], Ae[d],      s0);  s1 = fmaf(x[d], Ae[DH+d],  s1);
    s2 = fmaf(x[d], At_[d],     s2);  s3 = fmaf(x[d], At_[DH+d], s3);
    s4 = fmaf(x[d], Aq[d],      s4);  s5 = fmaf(x[d], Aq[DH+d],  s5);
  }
  qa_e[i]=s0; ka_e[i]=s1; qa_t[i]=s2; ka_t[i]=s3; qa_q[i]=s4; ka_q[i]=s5;
}

// ---------------- wave-synchronous hop: one wave per node, no barriers ----------------
// Denominator comes free: during gather every lane sums the alpha[m][hg] it reads anyway.
template<int EB>
__device__ __forceinline__ void hop_wave(
    int st, int deg, const u32* __restrict__ csg, const u32* __restrict__ eRec, int L4,
    const float* __restrict__ ka, const float* __restrict__ qa, const float* __restrict__ acoef,
    const __half* __restrict__ hh16, float* __restrict__ sa, int n, int l, int hg,
    float& o0, float& o1){
  float4 qv0 = *(const float4*)(qa + (size_t)n*8);
  float4 qv1 = *(const float4*)(qa + (size_t)n*8 + 4);
  float qa8[8] = {qv0.x,qv0.y,qv0.z,qv0.w,qv1.x,qv1.y,qv1.z,qv1.w};
  float cf[8];
  #pragma unroll
  for (int h=0;h<8;h++) cf[h] = acoef[h*33+32];
  float acc0=0.f, acc1=0.f, dsum=0.f;
  for (int base=0; base<deg; base+=CAP){
    int c = min(CAP, deg-base);
    u32 sg = 0;
    if (l < c){
      size_t idx = (size_t)(st+base+l);
      float bias8[8] = {0,0,0,0,0,0,0,0};
      if (EB){
        sg = eRec[idx*16];
        u32x4 br = *(const u32x4*)(eRec + idx*16 + 4 + L4);
        #pragma unroll
        for (int h=0;h<8;h++){
          u32 bw = br[h>>1];
          unsigned short us = (h&1)? (unsigned short)(bw>>16) : (unsigned short)(bw&0xFFFFu);
          bias8[h] = __half2float(__ushort_as_half(us));
        }
      } else {
        sg = csg[idx];
      }
      int src = (int)(sg>>16);
      float g = __half2float(__ushort_as_half((unsigned short)(sg&0xFFFFu)));
      float4 k0 = *(const float4*)(ka + (size_t)src*8);
      float4 k1 = *(const float4*)(ka + (size_t)src*8 + 4);
      float ka8[8] = {k0.x,k0.y,k0.z,k0.w,k1.x,k1.y,k1.z,k1.w};
      #pragma unroll
      for (int h=0;h<8;h++){
        float lg = qa8[h] + ka8[h] + g*cf[h] + bias8[h];
        lg = lg>=0.f ? lg : 0.2f*lg;
        sa[l*9+h] = __expf(lg);
      }
    }
    __builtin_amdgcn_wave_barrier();
    #pragma unroll 4
    for (int m=0; m<c; ++m){
      float am = sa[m*9+hg];
      u32 sv = __shfl(sg, m);
      int src = (int)(sv>>16);
      float2 f = __half22float2(*(const __half2*)&hh16[(size_t)src*HID + 2*l]);
      dsum += am;
      acc0 = fmaf(f.x, am, acc0);
      acc1 = fmaf(f.y, am, acc1);
    }
    __builtin_amdgcn_wave_barrier();
  }
  float inv = 1.f/(dsum + 1e-16f);
  o0 = fmaf(acc0, inv, o0);
  o1 = fmaf(acc1, inv, o1);
}

// ---------------- fused 3-hop attention + residual + ELU; 4 waves/block, 1 wave per node ----
__global__ __launch_bounds__(256) void k_hop3(
    const int* __restrict__ off_e, const int* __restrict__ off_t, const int* __restrict__ off_q,
    const u32* __restrict__ eRec,
    const u32* __restrict__ csg_t, const u32* __restrict__ csg_q,
    const float* __restrict__ qa_e, const float* __restrict__ ka_e,
    const float* __restrict__ qa_t, const float* __restrict__ ka_t,
    const float* __restrict__ qa_q, const float* __restrict__ ka_q,
    const float* __restrict__ ae, const float* __restrict__ at, const float* __restrict__ aq,
    const __half* __restrict__ hh16, const __half* __restrict__ hlr16, float* __restrict__ hout,
    int L){
  __shared__ float sh_a[4][CAP*9];   // stride-9: conflict-free writes (9 coprime 32) and reads
  int t = threadIdx.x;
  int wv = t>>6, l = t&63;
  int n = blockIdx.x*4 + wv;
  if (n >= NN) return;
  float* sa = sh_a[wv];
  int hg = l>>3;
  float o0=0.f, o1=0.f;
  int se = off_e[n], de = off_e[n+1]-se;
  int st = off_t[n], dt = off_t[n+1]-st;
  int sq = off_q[n], dq = off_q[n+1]-sq;
  hop_wave<1>(se, de, nullptr, eRec, 4*L, ka_e, qa_e, ae, hh16, sa, n, l, hg, o0, o1);
  hop_wave<0>(st, dt, csg_t, nullptr, 0,  ka_t, qa_t, at, hh16, sa, n, l, hg, o0, o1);
  hop_wave<0>(sq, dq, csg_q, nullptr, 0,  ka_q, qa_q, aq, hh16, sa, n, l, hg, o0, o1);
  size_t oi = (size_t)n*HID + 2*l;
  float2 rf = __half22float2(*(const __half2*)&hlr16[oi]);
  *(float2*)&hout[oi] = make_float2(eluf(rf.x + o0), eluf(rf.y + o1));
}

// ---------------- pooling: sum + max per graph ----------------
__global__ __launch_bounds__(128) void k_pool(const float* __restrict__ h, const int* __restrict__ goff,
                                              float* __restrict__ gs, float* __restrict__ gmx){
  int g = blockIdx.x, t = threadIdx.x;
  int s = goff[g], e = goff[g+1];
  float sum = 0.f, mx = -INFINITY;
  for (int n=s; n<e; n++){
    float v = h[(size_t)n*HID+t];
    sum += v; mx = fmaxf(mx, v);
  }
  gs[(size_t)g*HID+t] = sum;
  gmx[(size_t)g*HID+t] = (s < e) ? mx : 0.f;
}

// ---------------- readout MLP: [257]->256->256->1, 8 graphs per block ----------------
#define GPB 8
#define MSTR 260
__global__ __launch_bounds__(256) void k_mlp(const float* __restrict__ gs, const float* __restrict__ gmx,
    const float* __restrict__ temps,
    const float* __restrict__ W1, const float* __restrict__ b1,
    const float* __restrict__ W2, const float* __restrict__ b2,
    const float* __restrict__ W3, const float* __restrict__ b3,
    float* __restrict__ out){
  __shared__ float mol[GPB][MSTR];
  __shared__ float hd[GPB][MSTR];
  int g0 = blockIdx.x*GPB, t = threadIdx.x;
  for (int i=t; i<GPB*HID; i+=256){
    int g=i>>7, d=i&127;
    mol[g][d]     = gs[(size_t)(g0+g)*HID+d];
    mol[g][128+d] = gmx[(size_t)(g0+g)*HID+d];
  }
  if (t < GPB){ mol[t][256]=temps[g0+t]; mol[t][257]=0.f; mol[t][258]=0.f; mol[t][259]=0.f; }
  __syncthreads();
  float acc[GPB];
  #pragma unroll
  for (int g=0;g<GPB;g++) acc[g]=b1[t];
  for (int k0=0;k0<256;k0+=4){
    float w0=W1[(size_t)(k0+0)*256+t], w1=W1[(size_t)(k0+1)*256+t];
    float w2=W1[(size_t)(k0+2)*256+t], w3=W1[(size_t)(k0+3)*256+t];
    #pragma unroll
    for (int g=0;g<GPB;g++){
      float4 m4 = *(const float4*)&mol[g][k0];
      acc[g] = fmaf(m4.x,w0, fmaf(m4.y,w1, fmaf(m4.z,w2, fmaf(m4.w,w3, acc[g]))));
    }
  }
  { float wl=W1[(size_t)256*256+t];
    #pragma unroll
    for (int g=0;g<GPB;g++) acc[g]=fmaf(mol[g][256],wl,acc[g]); }
  #pragma unroll
  for (int g=0;g<GPB;g++) hd[g][t]=eluf(acc[g]);
  __syncthreads();
  #pragma unroll
  for (int g=0;g<GPB;g++) acc[g]=b2[t];
  for (int k0=0;k0<256;k0+=4){
    float w0=W2[(size_t)(k0+0)*256+t], w1=W2[(size_t)(k0+1)*256+t];
    float w2=W2[(size_t)(k0+2)*256+t], w3=W2[(size_t)(k0+3)*256+t];
    #pragma unroll
    for (int g=0;g<GPB;g++){
      float4 h4 = *(const float4*)&hd[g][k0];
      acc[g] = fmaf(h4.x,w0, fmaf(h4.y,w1, fmaf(h4.z,w2, fmaf(h4.w,w3, acc[g]))));
    }
  }
  float w3v = W3[t];
  #pragma unroll
  for (int g=0;g<GPB;g++) mol[g][t] = eluf(acc[g])*w3v;
  __syncthreads();
  int g = t >> 5, j = t & 31;
  float s = 0.f;
  for (int i=j; i<256; i+=32) s += mol[g][i];
  #pragma unroll
  for (int d=16; d>0; d>>=1) s += __shfl_down(s, d, 32);
  if (j == 0) out[g0+g] = s + b3[0];
}

extern "C" void kernel_launch(void* const* d_in, const int* in_sizes, int n_in,
                              void* d_out, int out_size, void* d_ws, size_t ws_size,
                              hipStream_t stream){
  const float* x         = (const float*)d_in[0];
  const float* pos       = (const float*)d_in[1];
  const float* edge_attr = (const float*)d_in[2];
  const float* temps     = (const float*)d_in[3];
  const int*   ei        = (const int*)d_in[4];
  const int*   ti        = (const int*)d_in[5];
  const int*   qi        = (const int*)d_in[6];
  const int*   batch     = (const int*)d_in[7];
  const float* W         = (const float*)d_in[8];
  const float* a_e       = (const float*)d_in[9];
  const float* a_t       = (const float*)d_in[10];
  const float* a_q       = (const float*)d_in[11];
  const float* We        = (const float*)d_in[12];
  const float* W1        = (const float*)d_in[13];
  const float* b1        = (const float*)d_in[14];
  const float* W2        = (const float*)d_in[15];
  const float* b2        = (const float*)d_in[16];
  const float* W3        = (const float*)d_in[17];
  const float* b3        = (const float*)d_in[18];
  float* out = (float*)d_out;

  char* base = (char*)d_ws; size_t woff = 0;
  auto alloc = [&](size_t bytes)->void*{
    void* p = base + woff;
    woff = (woff + bytes + 255) & ~(size_t)255;
    return p;
  };
  float*  hbuf   = (float*)alloc((size_t)NN*HID*4);
  __half* hl16   = (__half*)alloc((size_t)NN*HID*2);
  float*  qa_e   = (float*)alloc((size_t)NN*NH*4);
  float*  ka_e   = (float*)alloc((size_t)NN*NH*4);
  float*  qa_t   = (float*)alloc((size_t)NN*NH*4);
  float*  ka_t   = (float*)alloc((size_t)NN*NH*4);
  float*  qa_q   = (float*)alloc((size_t)NN*NH*4);
  float*  ka_q   = (float*)alloc((size_t)NN*NH*4);
  u32*    eRec   = (u32*)alloc((size_t)EE*64);
  u32*    csg_t  = (u32*)alloc((size_t)TT*4);
  u32*    csg_q  = (u32*)alloc((size_t)QQ*4);
  uint2*  stg    = (uint2*)alloc((size_t)(TT+QQ)*8);
  float*  gs     = (float*)alloc((size_t)GG*HID*4);
  float*  gmx    = (float*)alloc((size_t)GG*HID*4);
  int*    cnt    = (int*)alloc((size_t)3*NN*4);
  u32*    gcur   = (u32*)alloc((size_t)NBG*4);
  int*    off_e  = (int*)alloc((size_t)(NN+1)*4);
  int*    off_t  = (int*)alloc((size_t)(NN+1)*4);
  int*    off_q  = (int*)alloc((size_t)(NN+1)*4);
  int*    cur_e  = (int*)alloc((size_t)NN*4);
  int*    cur_t  = (int*)alloc((size_t)NN*4);
  int*    cur_q  = (int*)alloc((size_t)NN*4);
  int*    goff   = (int*)alloc((size_t)(GG+1)*4);

  // ---- CSR build + geometry ----
  hipMemsetAsync(cnt, 0, (size_t)3*NN*4, stream);
  hipMemsetAsync(gcur, 0, (size_t)NBG*4, stream);
  int tot = EE+TT+QQ;
  k_count3<<<(tot+255)/256,256,0,stream>>>(ei, ti, qi, cnt);
  k_scan4<<<4,1024,0,stream>>>(cnt, off_e, off_t, off_q, cur_e, cur_t, cur_q, batch, goff);
  k_fillE<<<(EE+255)/256,256,0,stream>>>(pos, edge_attr, ei, We, cur_e, eRec);
  k_fillTQ_A<<<(TT+QQ+TILE-1)/TILE,256,0,stream>>>(pos, ti, qi, off_t, off_q, gcur, stg);
  k_fillTQ_B<<<NBG,256,0,stream>>>(stg, off_t, off_q, csg_t, csg_q);

  // ---- layers ----
  for (int l=0; l<3; l++){
    const float* hin = (l==0) ? x : hbuf;
    k_gemm<<<NN/GR,128,0,stream>>>(hin, W + (size_t)l*HID*HID, hl16);
    k_proj<<<(NN*NH+255)/256,256,0,stream>>>(hl16, a_e+l*264, a_t+l*264, a_q+l*264,
                                             qa_e, ka_e, qa_t, ka_t, qa_q, ka_q);
    k_hop3<<<(NN+3)/4,256,0,stream>>>(off_e, off_t, off_q, eRec, csg_t, csg_q,
                                      qa_e, ka_e, qa_t, ka_t, qa_q, ka_q,
                                      a_e+l*264, a_t+l*264, a_q+l*264,
                                      hl16, hl16, hbuf, l);
  }

  // ---- readout ----
  k_pool<<<GG,128,0,stream>>>(hbuf, goff, gs, gmx);
  k_mlp<<<GG/GPB,256,0,stream>>>(gs, gmx, temps, W1, b1, W2, b2, W3, b3, out);
}

// Round 10
// 1064.427 us; speedup vs baseline: 1.2273x; 1.1127x over previous
//
#include <hip/hip_runtime.h>
#include <hip/hip_fp16.h>

#define NN 50000
#define EE 800000
#define TT 1000000
#define QQ 1000000
#define GG 4096
#define HID 128
#define NH 8
#define DH 16
#define CAP 64
#define SLOT 5

#define TILE 2048
#define KPT 8
#define NB 196            // ceil(NN/256) buckets per type
#define NBG 392           // T buckets + Q buckets

typedef unsigned int u32;
typedef unsigned int u32x4 __attribute__((ext_vector_type(4)));

__device__ __forceinline__ float eluf(float x){ return x > 0.f ? x : expm1f(x); }

__device__ __forceinline__ u32 pack_sg(int src, float g){
  return ((u32)src << 16) | (u32)__half_as_ushort(__float2half(g));
}
__device__ __forceinline__ float lo16(u32 w){ return __half2float(__ushort_as_half((unsigned short)(w&0xFFFFu))); }
__device__ __forceinline__ float hi16(u32 w){ return __half2float(__ushort_as_half((unsigned short)(w>>16))); }
__device__ __forceinline__ u32 packf2(float a, float b){
  __half2 h = __floats2half2_rn(a,b);
  return *(u32*)&h;
}
__device__ __forceinline__ void unpack8(const __half* p, float* o){
  u32x4 w = *(const u32x4*)p;
  #pragma unroll
  for (int j=0;j<4;j++){ u32 x=w[j]; o[2*j]=lo16(x); o[2*j+1]=hi16(x); }
}

// ---------------- count incident interactions per dst node ----------------
__global__ void k_count3(const int* __restrict__ ei, const int* __restrict__ ti, const int* __restrict__ qi,
                         int* __restrict__ cnt){
  int i = blockIdx.x*blockDim.x + threadIdx.x;
  if (i < EE) atomicAdd(&cnt[ei[i]], 1);
  else if (i < EE+TT) atomicAdd(&cnt[NN + ti[i-EE]], 1);
  else if (i < EE+TT+QQ) atomicAdd(&cnt[2*NN + qi[i-EE-TT]], 1);
}

// ---------------- 3 scans (off+cur) + graph offsets ----------------
__global__ __launch_bounds__(1024) void k_scan4(const int* __restrict__ cnt,
    int* __restrict__ off_e, int* __restrict__ off_t, int* __restrict__ off_q,
    int* __restrict__ cur_e, int* __restrict__ cur_t, int* __restrict__ cur_q,
    const int* __restrict__ batch, int* __restrict__ goff){
  int b = blockIdx.x, t = threadIdx.x;
  if (b == 3){
    for (int g=t; g<=GG; g+=1024){
      int lo=0, hi=NN;
      while (lo<hi){ int mid=(lo+hi)>>1; if (batch[mid]<g) lo=mid+1; else hi=mid; }
      goff[g]=lo;
    }
    return;
  }
  __shared__ int part[1024];
  const int* c = cnt + b*NN;
  int* off = (b==0)?off_e:(b==1)?off_t:off_q;
  int* cur = (b==0)?cur_e:(b==1)?cur_t:cur_q;
  int chunk = (NN + 1023) >> 10;
  int s0 = t*chunk, s1 = min(NN, s0+chunk);
  int sum = 0;
  for (int i=s0;i<s1;i++) sum += c[i];
  part[t] = sum;
  __syncthreads();
  for (int d=1; d<1024; d<<=1){
    int v = (t>=d) ? part[t-d] : 0;
    __syncthreads();
    part[t] += v;
    __syncthreads();
  }
  int run = (t==0) ? 0 : part[t-1];
  for (int i=s0;i<s1;i++){ off[i]=run; cur[i]=run; run += c[i]; }
  if (t==0) off[NN] = part[1023];
}

// ---------------- E edges: one 64B record per edge ----------------
__global__ void k_fillE(const float* __restrict__ pos, const float* __restrict__ edge_attr,
    const int* __restrict__ ei, const float* __restrict__ We,
    int* __restrict__ cur_e, u32* __restrict__ eRec){
  int i = blockIdx.x*blockDim.x + threadIdx.x;
  if (i >= EE) return;
  int dn = ei[i], sn = ei[EE+i];
  float dx = pos[dn*3+0]-pos[sn*3+0]+1e-8f;
  float dy = pos[dn*3+1]-pos[sn*3+1]+1e-8f;
  float dz = pos[dn*3+2]-pos[sn*3+2]+1e-8f;
  float d = sqrtf(dx*dx+dy*dy+dz*dz);
  int p = atomicAdd(&cur_e[dn], 1);
  const float4* s = (const float4*)(edge_attr + (size_t)i*16);
  float4 v0=s[0], v1=s[1], v2=s[2], v3=s[3];
  float a[16] = {v0.x,v0.y,v0.z,v0.w, v1.x,v1.y,v1.z,v1.w,
                 v2.x,v2.y,v2.z,v2.w, v3.x,v3.y,v3.z,v3.w};
  u32x4 r[4];
  r[0][0] = pack_sg(sn, d); r[0][1]=0; r[0][2]=0; r[0][3]=0;
  #pragma unroll
  for (int l=0; l<3; l++){
    const float* Wel = We + l*DH*NH;
    #pragma unroll
    for (int hp=0; hp<4; hp++){
      float sa=0.f, sb=0.f;
      #pragma unroll
      for (int c=0;c<16;c++){
        sa = fmaf(a[c], Wel[c*NH + 2*hp],     sa);
        sb = fmaf(a[c], Wel[c*NH + 2*hp + 1], sb);
      }
      r[1+l][hp] = packf2(sa, sb);
    }
  }
  u32x4* dst4 = (u32x4*)(eRec + (size_t)p*16);
  dst4[0]=r[0]; dst4[1]=r[1]; dst4[2]=r[2]; dst4[3]=r[3];
}

// ---------------- T/Q stage A: tile counting-sort by dst-bucket ----------------
__global__ __launch_bounds__(256) void k_fillTQ_A(const float* __restrict__ pos,
    const int* __restrict__ ti, const int* __restrict__ qi,
    const int* __restrict__ off_t, const int* __restrict__ off_q,
    u32* __restrict__ gcur, uint2* __restrict__ stg){
  __shared__ u32 s_sg[TILE];
  __shared__ u32 s_dw[TILE];
  __shared__ u32 s_cnt[NBG];
  __shared__ u32 s_scan[512];
  __shared__ u32 s_gb[NBG];
  int t = threadIdx.x;
  size_t tile0 = (size_t)blockIdx.x * TILE;
  for (int i=t;i<NBG;i+=256) s_cnt[i]=0;
  __syncthreads();
  u32 my_sg[KPT], my_dw[KPT], my_rank[KPT]; int my_bg[KPT];
  #pragma unroll
  for (int k=0;k<KPT;k++){
    size_t idx = tile0 + (size_t)k*256 + t;
    my_bg[k] = -1;
    if (idx < (size_t)TT+QQ){
      int dst, src; float g;
      int typeq = (idx >= (size_t)TT);
      if (!typeq){
        int m = (int)idx;
        int ia=ti[m], jb=ti[TT+m], kc=ti[2*TT+m];
        float ux=pos[ia*3+0]-pos[jb*3+0], uy=pos[ia*3+1]-pos[jb*3+1], uz=pos[ia*3+2]-pos[jb*3+2];
        float vx=pos[kc*3+0]-pos[jb*3+0], vy=pos[kc*3+1]-pos[jb*3+1], vz=pos[kc*3+2]-pos[jb*3+2];
        float num = ux*vx+uy*vy+uz*vz;
        float den = sqrtf(ux*ux+uy*uy+uz*uz)*sqrtf(vx*vx+vy*vy+vz*vz) + 1e-8f;
        g = num/den; dst = ia; src = kc;
      } else {
        int m = (int)(idx - TT);
        int p0=qi[m], p1=qi[QQ+m], p2=qi[2*QQ+m], p3=qi[3*QQ+m];
        float b1x=pos[p1*3+0]-pos[p0*3+0], b1y=pos[p1*3+1]-pos[p0*3+1], b1z=pos[p1*3+2]-pos[p0*3+2];
        float b2x=pos[p2*3+0]-pos[p1*3+0], b2y=pos[p2*3+1]-pos[p1*3+1], b2z=pos[p2*3+2]-pos[p1*3+2];
        float b3x=pos[p3*3+0]-pos[p2*3+0], b3y=pos[p3*3+1]-pos[p2*3+1], b3z=pos[p3*3+2]-pos[p2*3+2];
        float n1x=b1y*b2z-b1z*b2y, n1y=b1z*b2x-b1x*b2z, n1z=b1x*b2y-b1y*b2x;
        float n2x=b2y*b3z-b2z*b3y, n2y=b2z*b3x-b2x*b3z, n2z=b2x*b3y-b2y*b3x;
        float num = n1x*n2x+n1y*n2y+n1z*n2z;
        float den = sqrtf(n1x*n1x+n1y*n1y+n1z*n1z)*sqrtf(n2x*n2x+n2y*n2y+n2z*n2z) + 1e-8f;
        g = num/den; dst = p0; src = p3;
      }
      int bg = (typeq?NB:0) + (dst>>8);
      my_sg[k] = pack_sg(src, g);
      my_dw[k] = (u32)dst | ((u32)typeq<<20);
      my_bg[k] = bg;
      my_rank[k] = atomicAdd(&s_cnt[bg], 1u);
    }
  }
  __syncthreads();
  int i0=t, i1=t+256;
  s_scan[i0] = (i0<NBG)? s_cnt[i0] : 0u;
  s_scan[i1] = (i1<NBG)? s_cnt[i1] : 0u;
  __syncthreads();
  for (int d=1; d<512; d<<=1){
    u32 a0 = (i0>=d)? s_scan[i0-d] : 0u;
    u32 a1 = (i1>=d)? s_scan[i1-d] : 0u;
    __syncthreads();
    s_scan[i0]+=a0; s_scan[i1]+=a1;
    __syncthreads();
  }
  u32 total = s_scan[NBG-1];
  #pragma unroll
  for (int k=0;k<KPT;k++){
    if (my_bg[k]>=0){
      u32 slot = s_scan[my_bg[k]] - s_cnt[my_bg[k]] + my_rank[k];
      s_sg[slot]=my_sg[k]; s_dw[slot]=my_dw[k];
    }
  }
  for (int i=t;i<NBG;i+=256)
    s_gb[i] = s_cnt[i] ? atomicAdd(&gcur[i], s_cnt[i]) : 0u;
  __syncthreads();
  for (u32 j=t; j<total; j+=256){
    u32 dw = s_dw[j];
    int typeq = (dw>>20)&1;
    int dst = dw & 0xFFFFF;
    int bg = (typeq?NB:0) + (dst>>8);
    u32 rank = j - (s_scan[bg]-s_cnt[bg]);
    int w0 = (typeq? bg-NB : bg)*256;
    size_t sbase = typeq ? (size_t)TT + (size_t)off_q[w0] : (size_t)off_t[w0];
    stg[sbase + s_gb[bg] + rank] = make_uint2(s_sg[j], dw);
  }
}

// ---------------- T/Q stage B: per-bucket placement ----------------
__global__ __launch_bounds__(256) void k_fillTQ_B(const uint2* __restrict__ stg,
    const int* __restrict__ off_t, const int* __restrict__ off_q,
    u32* __restrict__ csg_t, u32* __restrict__ csg_q){
  __shared__ int curL[256];
  int b = blockIdx.x, t = threadIdx.x;
  int typeq = (b>=NB);
  int bl = typeq? b-NB : b;
  const int* off = typeq? off_q : off_t;
  u32* csg = typeq? csg_q : csg_t;
  int w0 = bl*256, w1 = min(w0+256, NN);
  int s0 = off[w0], s1 = off[w1];
  for (int i=t; i<w1-w0; i+=256) curL[i] = off[w0+i];
  __syncthreads();
  size_t sb = (typeq? (size_t)TT : 0) + (size_t)s0;
  int cnt = s1 - s0;
  for (int i=t; i<cnt; i+=256){
    uint2 r = stg[sb+i];
    int dst = r.y & 0xFFFFF;
    int p = atomicAdd(&curL[dst-w0], 1);
    csg[p] = r.x;
  }
}

// ---------------- GEMM + fused proj: hl16 = fp16(A@W); qa/ka (fp16) for 3 hop types ----------------
#define GR 16
__global__ __launch_bounds__(128) void k_gemm(const float* __restrict__ A, const float* __restrict__ Wm,
    const float* __restrict__ ae, const float* __restrict__ at, const float* __restrict__ aq,
    __half* __restrict__ B16,
    __half* __restrict__ qa_e, __half* __restrict__ ka_e,
    __half* __restrict__ qa_t, __half* __restrict__ ka_t,
    __half* __restrict__ qa_q, __half* __restrict__ ka_q){
  __shared__ float sh[GR][132];
  int col = threadIdx.x;
  int r0 = blockIdx.x * GR;
  const float* Ab = A + (size_t)r0*HID;
  float acc[GR];
  #pragma unroll
  for (int r=0;r<GR;r++) acc[r]=0.f;
  #pragma unroll 4
  for (int k=0;k<HID;k++){
    float wv = Wm[k*HID+col];
    #pragma unroll
    for (int r=0;r<GR;r++) acc[r] = fmaf(Ab[r*HID+k], wv, acc[r]);
  }
  #pragma unroll
  for (int r=0;r<GR;r++){
    B16[(size_t)(r0+r)*HID+col] = __float2half(acc[r]);
    sh[r][col] = acc[r];
  }
  __syncthreads();
  int r = threadIdx.x>>3, h = threadIdx.x&7;
  float x[DH];
  #pragma unroll
  for (int j=0;j<DH;j++) x[j] = sh[r][h*DH+j];
  const float* Ae = ae + h*33; const float* At_ = at + h*33; const float* Aq = aq + h*33;
  float s0=0,s1=0,s2=0,s3=0,s4=0,s5=0;
  #pragma unroll
  for (int d=0; d<DH; d++){
    s0 = fmaf(x[d], Ae[d],      s0);  s1 = fmaf(x[d], Ae[DH+d],  s1);
    s2 = fmaf(x[d], At_[d],     s2);  s3 = fmaf(x[d], At_[DH+d], s3);
    s4 = fmaf(x[d], Aq[d],      s4);  s5 = fmaf(x[d], Aq[DH+d],  s5);
  }
  size_t o = (size_t)(r0+r)*NH + h;
  qa_e[o]=__float2half(s0); ka_e[o]=__float2half(s1);
  qa_t[o]=__float2half(s2); ka_t[o]=__float2half(s3);
  qa_q[o]=__float2half(s4); ka_q[o]=__float2half(s5);
}

// ---------------- fused 3-hop attention; wave-per-node, unified logit phase ----------------
__global__ __launch_bounds__(256) void k_hop3(
    const int* __restrict__ off_e, const int* __restrict__ off_t, const int* __restrict__ off_q,
    const u32* __restrict__ eRec,
    const u32* __restrict__ csg_t, const u32* __restrict__ csg_q,
    const __half* __restrict__ qa_e, const __half* __restrict__ ka_e,
    const __half* __restrict__ qa_t, const __half* __restrict__ ka_t,
    const __half* __restrict__ qa_q, const __half* __restrict__ ka_q,
    const float* __restrict__ ae, const float* __restrict__ at, const float* __restrict__ aq,
    const __half* __restrict__ hh16, const __half* __restrict__ hlr16, float* __restrict__ hout,
    int L, int nwaves){
  __shared__ u32 sw[4][3*CAP*SLOT];   // 15360 B: packed fp16 alpha x4 + src per edge
  int t = threadIdx.x;
  int wv = t>>6, l = t&63;
  u32* Wb = sw[wv];
  int hg = l>>3;
  int wi = hg>>1, shft = (hg&1)*16;
  // per-head geometry coefficients: uniform -> scalar loads
  float cfE[8], cfT[8], cfQ[8];
  #pragma unroll
  for (int h=0;h<8;h++){ cfE[h]=ae[h*33+32]; cfT[h]=at[h*33+32]; cfQ[h]=aq[h*33+32]; }
  for (int n = blockIdx.x*4 + wv; n < NN; n += nwaves){
    int se=off_e[n], de=off_e[n+1]-se;
    int st=off_t[n], dt=off_t[n+1]-st;
    int sq=off_q[n], dq=off_q[n+1]-sq;
    float aE0=0,aE1=0,aT0=0,aT1=0,aQ0=0,aQ1=0,dE=0,dT=0,dQ=0;
    int maxd = max(de, max(dt, dq));
    for (int base=0; base<maxd; base+=CAP){
      int ce = min(CAP, de-base); if (ce<0) ce=0;
      int ct = min(CAP, dt-base); if (ct<0) ct=0;
      int cq = min(CAP, dq-base); if (cq<0) cq=0;
      // ---- unified logit phase: all three hops' loads in flight ----
      if (l < ce){
        size_t idx = (size_t)(se+base+l);
        u32 sg = eRec[idx*16];
        u32x4 br = *(const u32x4*)(eRec + idx*16 + 4 + 4*L);
        int src = (int)(sg>>16);
        float g = lo16(sg);
        float ka8[8]; unpack8(ka_e + (size_t)src*NH, ka8);
        float qa8[8]; unpack8(qa_e + (size_t)n*NH, qa8);
        u32* sl = Wb + l*SLOT;
        #pragma unroll
        for (int j=0;j<4;j++){
          u32 bw = br[j];
          float l0 = qa8[2*j]   + ka8[2*j]   + g*cfE[2*j]   + lo16(bw);
          float l1 = qa8[2*j+1] + ka8[2*j+1] + g*cfE[2*j+1] + hi16(bw);
          l0 = l0>=0.f ? l0 : 0.2f*l0;
          l1 = l1>=0.f ? l1 : 0.2f*l1;
          sl[j] = packf2(__expf(l0), __expf(l1));
        }
        sl[4] = (u32)src;
      }
      if (l < ct){
        u32 sg = csg_t[(size_t)(st+base+l)];
        int src = (int)(sg>>16);
        float g = lo16(sg);
        float ka8[8]; unpack8(ka_t + (size_t)src*NH, ka8);
        float qa8[8]; unpack8(qa_t + (size_t)n*NH, qa8);
        u32* sl = Wb + CAP*SLOT + l*SLOT;
        #pragma unroll
        for (int j=0;j<4;j++){
          float l0 = qa8[2*j]   + ka8[2*j]   + g*cfT[2*j];
          float l1 = qa8[2*j+1] + ka8[2*j+1] + g*cfT[2*j+1];
          l0 = l0>=0.f ? l0 : 0.2f*l0;
          l1 = l1>=0.f ? l1 : 0.2f*l1;
          sl[j] = packf2(__expf(l0), __expf(l1));
        }
        sl[4] = (u32)src;
      }
      if (l < cq){
        u32 sg = csg_q[(size_t)(sq+base+l)];
        int src = (int)(sg>>16);
        float g = lo16(sg);
        float ka8[8]; unpack8(ka_q + (size_t)src*NH, ka8);
        float qa8[8]; unpack8(qa_q + (size_t)n*NH, qa8);
        u32* sl = Wb + 2*CAP*SLOT + l*SLOT;
        #pragma unroll
        for (int j=0;j<4;j++){
          float l0 = qa8[2*j]   + ka8[2*j]   + g*cfQ[2*j];
          float l1 = qa8[2*j+1] + ka8[2*j+1] + g*cfQ[2*j+1];
          l0 = l0>=0.f ? l0 : 0.2f*l0;
          l1 = l1>=0.f ? l1 : 0.2f*l1;
          sl[j] = packf2(__expf(l0), __expf(l1));
        }
        sl[4] = (u32)src;
      }
      __builtin_amdgcn_wave_barrier();
      // ---- gather phase: three tight loops back-to-back ----
      {
        const u32* P = Wb;
        #pragma unroll 4
        for (int m=0;m<ce;m++){
          u32 aw = P[m*SLOT+wi];
          u32 sr = P[m*SLOT+4];
          float am = __half2float(__ushort_as_half((unsigned short)(aw>>shft)));
          float2 f = __half22float2(*((const __half2*)(hh16 + (size_t)sr*HID) + l));
          dE += am; aE0 = fmaf(f.x, am, aE0); aE1 = fmaf(f.y, am, aE1);
        }
      }
      {
        const u32* P = Wb + CAP*SLOT;
        #pragma unroll 4
        for (int m=0;m<ct;m++){
          u32 aw = P[m*SLOT+wi];
          u32 sr = P[m*SLOT+4];
          float am = __half2float(__ushort_as_half((unsigned short)(aw>>shft)));
          float2 f = __half22float2(*((const __half2*)(hh16 + (size_t)sr*HID) + l));
          dT += am; aT0 = fmaf(f.x, am, aT0); aT1 = fmaf(f.y, am, aT1);
        }
      }
      {
        const u32* P = Wb + 2*CAP*SLOT;
        #pragma unroll 4
        for (int m=0;m<cq;m++){
          u32 aw = P[m*SLOT+wi];
          u32 sr = P[m*SLOT+4];
          float am = __half2float(__ushort_as_half((unsigned short)(aw>>shft)));
          float2 f = __half22float2(*((const __half2*)(hh16 + (size_t)sr*HID) + l));
          dQ += am; aQ0 = fmaf(f.x, am, aQ0); aQ1 = fmaf(f.y, am, aQ1);
        }
      }
      __builtin_amdgcn_wave_barrier();
    }
    float invE = 1.f/(dE + 1e-16f);
    float invT = 1.f/(dT + 1e-16f);
    float invQ = 1.f/(dQ + 1e-16f);
    float o0 = aE0*invE + aT0*invT + aQ0*invQ;
    float o1 = aE1*invE + aT1*invT + aQ1*invQ;
    size_t oi = (size_t)n*HID + 2*l;
    float2 rf = __half22float2(*(const __half2*)&hlr16[oi]);
    *(float2*)&hout[oi] = make_float2(eluf(rf.x + o0), eluf(rf.y + o1));
  }
}

// ---------------- pooling: sum + max per graph ----------------
__global__ __launch_bounds__(128) void k_pool(const float* __restrict__ h, const int* __restrict__ goff,
                                              float* __restrict__ gs, float* __restrict__ gmx){
  int g = blockIdx.x, t = threadIdx.x;
  int s = goff[g], e = goff[g+1];
  float sum = 0.f, mx = -INFINITY;
  for (int n=s; n<e; n++){
    float v = h[(size_t)n*HID+t];
    sum += v; mx = fmaxf(mx, v);
  }
  gs[(size_t)g*HID+t] = sum;
  gmx[(size_t)g*HID+t] = (s < e) ? mx : 0.f;
}

// ---------------- readout MLP: [257]->256->256->1, 8 graphs per block ----------------
#define GPB 8
#define MSTR 260
__global__ __launch_bounds__(256) void k_mlp(const float* __restrict__ gs, const float* __restrict__ gmx,
    const float* __restrict__ temps,
    const float* __restrict__ W1, const float* __restrict__ b1,
    const float* __restrict__ W2, const float* __restrict__ b2,
    const float* __restrict__ W3, const float* __restrict__ b3,
    float* __restrict__ out){
  __shared__ float mol[GPB][MSTR];
  __shared__ float hd[GPB][MSTR];
  int g0 = blockIdx.x*GPB, t = threadIdx.x;
  for (int i=t; i<GPB*HID; i+=256){
    int g=i>>7, d=i&127;
    mol[g][d]     = gs[(size_t)(g0+g)*HID+d];
    mol[g][128+d] = gmx[(size_t)(g0+g)*HID+d];
  }
  if (t < GPB){ mol[t][256]=temps[g0+t]; mol[t][257]=0.f; mol[t][258]=0.f; mol[t][259]=0.f; }
  __syncthreads();
  float acc[GPB];
  #pragma unroll
  for (int g=0;g<GPB;g++) acc[g]=b1[t];
  for (int k0=0;k0<256;k0+=4){
    float w0=W1[(size_t)(k0+0)*256+t], w1=W1[(size_t)(k0+1)*256+t];
    float w2=W1[(size_t)(k0+2)*256+t], w3=W1[(size_t)(k0+3)*256+t];
    #pragma unroll
    for (int g=0;g<GPB;g++){
      float4 m4 = *(const float4*)&mol[g][k0];
      acc[g] = fmaf(m4.x,w0, fmaf(m4.y,w1, fmaf(m4.z,w2, fmaf(m4.w,w3, acc[g]))));
    }
  }
  { float wl=W1[(size_t)256*256+t];
    #pragma unroll
    for (int g=0;g<GPB;g++) acc[g]=fmaf(mol[g][256],wl,acc[g]); }
  #pragma unroll
  for (int g=0;g<GPB;g++) hd[g][t]=eluf(acc[g]);
  __syncthreads();
  #pragma unroll
  for (int g=0;g<GPB;g++) acc[g]=b2[t];
  for (int k0=0;k0<256;k0+=4){
    float w0=W2[(size_t)(k0+0)*256+t], w1=W2[(size_t)(k0+1)*256+t];
    float w2=W2[(size_t)(k0+2)*256+t], w3=W2[(size_t)(k0+3)*256+t];
    #pragma unroll
    for (int g=0;g<GPB;g++){
      float4 h4 = *(const float4*)&hd[g][k0];
      acc[g] = fmaf(h4.x,w0, fmaf(h4.y,w1, fmaf(h4.z,w2, fmaf(h4.w,w3, acc[g]))));
    }
  }
  float w3v = W3[t];
  #pragma unroll
  for (int g=0;g<GPB;g++) mol[g][t] = eluf(acc[g])*w3v;
  __syncthreads();
  int g = t >> 5, j = t & 31;
  float s = 0.f;
  for (int i=j; i<256; i+=32) s += mol[g][i];
  #pragma unroll
  for (int d=16; d>0; d>>=1) s += __shfl_down(s, d, 32);
  if (j == 0) out[g0+g] = s + b3[0];
}

extern "C" void kernel_launch(void* const* d_in, const int* in_sizes, int n_in,
                              void* d_out, int out_size, void* d_ws, size_t ws_size,
                              hipStream_t stream){
  const float* x         = (const float*)d_in[0];
  const float* pos       = (const float*)d_in[1];
  const float* edge_attr = (const float*)d_in[2];
  const float* temps     = (const float*)d_in[3];
  const int*   ei        = (const int*)d_in[4];
  const int*   ti        = (const int*)d_in[5];
  const int*   qi        = (const int*)d_in[6];
  const int*   batch     = (const int*)d_in[7];
  const float* W         = (const float*)d_in[8];
  const float* a_e       = (const float*)d_in[9];
  const float* a_t       = (const float*)d_in[10];
  const float* a_q       = (const float*)d_in[11];
  const float* We        = (const float*)d_in[12];
  const float* W1        = (const float*)d_in[13];
  const float* b1        = (const float*)d_in[14];
  const float* W2        = (const float*)d_in[15];
  const float* b2        = (const float*)d_in[16];
  const float* W3        = (const float*)d_in[17];
  const float* b3        = (const float*)d_in[18];
  float* out = (float*)d_out;

  char* base = (char*)d_ws; size_t woff = 0;
  auto alloc = [&](size_t bytes)->void*{
    void* p = base + woff;
    woff = (woff + bytes + 255) & ~(size_t)255;
    return p;
  };
  float*  hbuf   = (float*)alloc((size_t)NN*HID*4);
  __half* hl16   = (__half*)alloc((size_t)NN*HID*2);
  __half* qa_e   = (__half*)alloc((size_t)NN*NH*2);
  __half* ka_e   = (__half*)alloc((size_t)NN*NH*2);
  __half* qa_t   = (__half*)alloc((size_t)NN*NH*2);
  __half* ka_t   = (__half*)alloc((size_t)NN*NH*2);
  __half* qa_q   = (__half*)alloc((size_t)NN*NH*2);
  __half* ka_q   = (__half*)alloc((size_t)NN*NH*2);
  u32*    eRec   = (u32*)alloc((size_t)EE*64);
  u32*    csg_t  = (u32*)alloc((size_t)TT*4);
  u32*    csg_q  = (u32*)alloc((size_t)QQ*4);
  uint2*  stg    = (uint2*)alloc((size_t)(TT+QQ)*8);
  float*  gs     = (float*)alloc((size_t)GG*HID*4);
  float*  gmx    = (float*)alloc((size_t)GG*HID*4);
  int*    cnt    = (int*)alloc((size_t)3*NN*4);
  u32*    gcur   = (u32*)alloc((size_t)NBG*4);
  int*    off_e  = (int*)alloc((size_t)(NN+1)*4);
  int*    off_t  = (int*)alloc((size_t)(NN+1)*4);
  int*    off_q  = (int*)alloc((size_t)(NN+1)*4);
  int*    cur_e  = (int*)alloc((size_t)NN*4);
  int*    cur_t  = (int*)alloc((size_t)NN*4);
  int*    cur_q  = (int*)alloc((size_t)NN*4);
  int*    goff   = (int*)alloc((size_t)(GG+1)*4);

  // ---- CSR build + geometry ----
  hipMemsetAsync(cnt, 0, (size_t)3*NN*4, stream);
  hipMemsetAsync(gcur, 0, (size_t)NBG*4, stream);
  int tot = EE+TT+QQ;
  k_count3<<<(tot+255)/256,256,0,stream>>>(ei, ti, qi, cnt);
  k_scan4<<<4,1024,0,stream>>>(cnt, off_e, off_t, off_q, cur_e, cur_t, cur_q, batch, goff);
  k_fillE<<<(EE+255)/256,256,0,stream>>>(pos, edge_attr, ei, We, cur_e, eRec);
  k_fillTQ_A<<<(TT+QQ+TILE-1)/TILE,256,0,stream>>>(pos, ti, qi, off_t, off_q, gcur, stg);
  k_fillTQ_B<<<NBG,256,0,stream>>>(stg, off_t, off_q, csg_t, csg_q);

  // ---- layers ----
  int hopBlocks = 2048;
  int nwaves = hopBlocks*4;
  for (int l=0; l<3; l++){
    const float* hin = (l==0) ? x : hbuf;
    k_gemm<<<NN/GR,128,0,stream>>>(hin, W + (size_t)l*HID*HID,
                                   a_e+l*264, a_t+l*264, a_q+l*264,
                                   hl16, qa_e, ka_e, qa_t, ka_t, qa_q, ka_q);
    k_hop3<<<hopBlocks,256,0,stream>>>(off_e, off_t, off_q, eRec, csg_t, csg_q,
                                       qa_e, ka_e, qa_t, ka_t, qa_q, ka_q,
                                       a_e+l*264, a_t+l*264, a_q+l*264,
                                       hl16, hl16, hbuf, l, nwaves);
  }

  // ---- readout ----
  k_pool<<<GG,128,0,stream>>>(hbuf, goff, gs, gmx);
  k_mlp<<<GG/GPB,256,0,stream>>>(gs, gmx, temps, W1, b1, W2, b2, W3, b3, out);
}

// Round 11
// 1020.103 us; speedup vs baseline: 1.2806x; 1.0435x over previous
//
#include <hip/hip_runtime.h>
#include <hip/hip_fp16.h>

#define NN 50000
#define EE 800000
#define TT 1000000
#define QQ 1000000
#define GG 4096
#define HID 128
#define NH 8
#define DH 16
#define CAP 64
#define SLOT 5

#define TILE 2048
#define KPT 8
#define NB 196            // ceil(NN/256) buckets per type
#define NBG 392           // T buckets + Q buckets

typedef unsigned int u32;
typedef unsigned int u32x4 __attribute__((ext_vector_type(4)));

__device__ __forceinline__ float eluf(float x){ return x > 0.f ? x : expm1f(x); }

__device__ __forceinline__ u32 pack_sg(int src, float g){
  return ((u32)src << 16) | (u32)__half_as_ushort(__float2half(g));
}
__device__ __forceinline__ float lo16(u32 w){ return __half2float(__ushort_as_half((unsigned short)(w&0xFFFFu))); }
__device__ __forceinline__ float hi16(u32 w){ return __half2float(__ushort_as_half((unsigned short)(w>>16))); }
__device__ __forceinline__ u32 packf2(float a, float b){
  __half2 h = __floats2half2_rn(a,b);
  return *(u32*)&h;
}
__device__ __forceinline__ void unpack8(const __half* p, float* o){
  u32x4 w = *(const u32x4*)p;
  #pragma unroll
  for (int j=0;j<4;j++){ u32 x=w[j]; o[2*j]=lo16(x); o[2*j+1]=hi16(x); }
}

// ---------------- count incident interactions per dst node ----------------
__global__ void k_count3(const int* __restrict__ ei, const int* __restrict__ ti, const int* __restrict__ qi,
                         int* __restrict__ cnt){
  int i = blockIdx.x*blockDim.x + threadIdx.x;
  if (i < EE) atomicAdd(&cnt[ei[i]], 1);
  else if (i < EE+TT) atomicAdd(&cnt[NN + ti[i-EE]], 1);
  else if (i < EE+TT+QQ) atomicAdd(&cnt[2*NN + qi[i-EE-TT]], 1);
}

// ---------------- 3 scans (off+cur) + graph offsets ----------------
__global__ __launch_bounds__(1024) void k_scan4(const int* __restrict__ cnt,
    int* __restrict__ off_e, int* __restrict__ off_t, int* __restrict__ off_q,
    int* __restrict__ cur_e, int* __restrict__ cur_t, int* __restrict__ cur_q,
    const int* __restrict__ batch, int* __restrict__ goff){
  int b = blockIdx.x, t = threadIdx.x;
  if (b == 3){
    for (int g=t; g<=GG; g+=1024){
      int lo=0, hi=NN;
      while (lo<hi){ int mid=(lo+hi)>>1; if (batch[mid]<g) lo=mid+1; else hi=mid; }
      goff[g]=lo;
    }
    return;
  }
  __shared__ int part[1024];
  const int* c = cnt + b*NN;
  int* off = (b==0)?off_e:(b==1)?off_t:off_q;
  int* cur = (b==0)?cur_e:(b==1)?cur_t:cur_q;
  int chunk = (NN + 1023) >> 10;
  int s0 = t*chunk, s1 = min(NN, s0+chunk);
  int sum = 0;
  for (int i=s0;i<s1;i++) sum += c[i];
  part[t] = sum;
  __syncthreads();
  for (int d=1; d<1024; d<<=1){
    int v = (t>=d) ? part[t-d] : 0;
    __syncthreads();
    part[t] += v;
    __syncthreads();
  }
  int run = (t==0) ? 0 : part[t-1];
  for (int i=s0;i<s1;i++){ off[i]=run; cur[i]=run; run += c[i]; }
  if (t==0) off[NN] = part[1023];
}

// ---------------- E edges: one 64B record per edge ----------------
__global__ void k_fillE(const float* __restrict__ pos, const float* __restrict__ edge_attr,
    const int* __restrict__ ei, const float* __restrict__ We,
    int* __restrict__ cur_e, u32* __restrict__ eRec){
  int i = blockIdx.x*blockDim.x + threadIdx.x;
  if (i >= EE) return;
  int dn = ei[i], sn = ei[EE+i];
  float dx = pos[dn*3+0]-pos[sn*3+0]+1e-8f;
  float dy = pos[dn*3+1]-pos[sn*3+1]+1e-8f;
  float dz = pos[dn*3+2]-pos[sn*3+2]+1e-8f;
  float d = sqrtf(dx*dx+dy*dy+dz*dz);
  int p = atomicAdd(&cur_e[dn], 1);
  const float4* s = (const float4*)(edge_attr + (size_t)i*16);
  float4 v0=s[0], v1=s[1], v2=s[2], v3=s[3];
  float a[16] = {v0.x,v0.y,v0.z,v0.w, v1.x,v1.y,v1.z,v1.w,
                 v2.x,v2.y,v2.z,v2.w, v3.x,v3.y,v3.z,v3.w};
  u32x4 r[4];
  r[0][0] = pack_sg(sn, d); r[0][1]=0; r[0][2]=0; r[0][3]=0;
  #pragma unroll
  for (int l=0; l<3; l++){
    const float* Wel = We + l*DH*NH;
    #pragma unroll
    for (int hp=0; hp<4; hp++){
      float sa=0.f, sb=0.f;
      #pragma unroll
      for (int c=0;c<16;c++){
        sa = fmaf(a[c], Wel[c*NH + 2*hp],     sa);
        sb = fmaf(a[c], Wel[c*NH + 2*hp + 1], sb);
      }
      r[1+l][hp] = packf2(sa, sb);
    }
  }
  u32x4* dst4 = (u32x4*)(eRec + (size_t)p*16);
  dst4[0]=r[0]; dst4[1]=r[1]; dst4[2]=r[2]; dst4[3]=r[3];
}

// ---------------- T/Q stage A: tile counting-sort by dst-bucket ----------------
__global__ __launch_bounds__(256) void k_fillTQ_A(const float* __restrict__ pos,
    const int* __restrict__ ti, const int* __restrict__ qi,
    const int* __restrict__ off_t, const int* __restrict__ off_q,
    u32* __restrict__ gcur, uint2* __restrict__ stg){
  __shared__ u32 s_sg[TILE];
  __shared__ u32 s_dw[TILE];
  __shared__ u32 s_cnt[NBG];
  __shared__ u32 s_scan[512];
  __shared__ u32 s_gb[NBG];
  int t = threadIdx.x;
  size_t tile0 = (size_t)blockIdx.x * TILE;
  for (int i=t;i<NBG;i+=256) s_cnt[i]=0;
  __syncthreads();
  u32 my_sg[KPT], my_dw[KPT], my_rank[KPT]; int my_bg[KPT];
  #pragma unroll
  for (int k=0;k<KPT;k++){
    size_t idx = tile0 + (size_t)k*256 + t;
    my_bg[k] = -1;
    if (idx < (size_t)TT+QQ){
      int dst, src; float g;
      int typeq = (idx >= (size_t)TT);
      if (!typeq){
        int m = (int)idx;
        int ia=ti[m], jb=ti[TT+m], kc=ti[2*TT+m];
        float ux=pos[ia*3+0]-pos[jb*3+0], uy=pos[ia*3+1]-pos[jb*3+1], uz=pos[ia*3+2]-pos[jb*3+2];
        float vx=pos[kc*3+0]-pos[jb*3+0], vy=pos[kc*3+1]-pos[jb*3+1], vz=pos[kc*3+2]-pos[jb*3+2];
        float num = ux*vx+uy*vy+uz*vz;
        float den = sqrtf(ux*ux+uy*uy+uz*uz)*sqrtf(vx*vx+vy*vy+vz*vz) + 1e-8f;
        g = num/den; dst = ia; src = kc;
      } else {
        int m = (int)(idx - TT);
        int p0=qi[m], p1=qi[QQ+m], p2=qi[2*QQ+m], p3=qi[3*QQ+m];
        float b1x=pos[p1*3+0]-pos[p0*3+0], b1y=pos[p1*3+1]-pos[p0*3+1], b1z=pos[p1*3+2]-pos[p0*3+2];
        float b2x=pos[p2*3+0]-pos[p1*3+0], b2y=pos[p2*3+1]-pos[p1*3+1], b2z=pos[p2*3+2]-pos[p1*3+2];
        float b3x=pos[p3*3+0]-pos[p2*3+0], b3y=pos[p3*3+1]-pos[p2*3+1], b3z=pos[p3*3+2]-pos[p2*3+2];
        float n1x=b1y*b2z-b1z*b2y, n1y=b1z*b2x-b1x*b2z, n1z=b1x*b2y-b1y*b2x;
        float n2x=b2y*b3z-b2z*b3y, n2y=b2z*b3x-b2x*b3z, n2z=b2x*b3y-b2y*b3x;
        float num = n1x*n2x+n1y*n2y+n1z*n2z;
        float den = sqrtf(n1x*n1x+n1y*n1y+n1z*n1z)*sqrtf(n2x*n2x+n2y*n2y+n2z*n2z) + 1e-8f;
        g = num/den; dst = p0; src = p3;
      }
      int bg = (typeq?NB:0) + (dst>>8);
      my_sg[k] = pack_sg(src, g);
      my_dw[k] = (u32)dst | ((u32)typeq<<20);
      my_bg[k] = bg;
      my_rank[k] = atomicAdd(&s_cnt[bg], 1u);
    }
  }
  __syncthreads();
  int i0=t, i1=t+256;
  s_scan[i0] = (i0<NBG)? s_cnt[i0] : 0u;
  s_scan[i1] = (i1<NBG)? s_cnt[i1] : 0u;
  __syncthreads();
  for (int d=1; d<512; d<<=1){
    u32 a0 = (i0>=d)? s_scan[i0-d] : 0u;
    u32 a1 = (i1>=d)? s_scan[i1-d] : 0u;
    __syncthreads();
    s_scan[i0]+=a0; s_scan[i1]+=a1;
    __syncthreads();
  }
  u32 total = s_scan[NBG-1];
  #pragma unroll
  for (int k=0;k<KPT;k++){
    if (my_bg[k]>=0){
      u32 slot = s_scan[my_bg[k]] - s_cnt[my_bg[k]] + my_rank[k];
      s_sg[slot]=my_sg[k]; s_dw[slot]=my_dw[k];
    }
  }
  for (int i=t;i<NBG;i+=256)
    s_gb[i] = s_cnt[i] ? atomicAdd(&gcur[i], s_cnt[i]) : 0u;
  __syncthreads();
  for (u32 j=t; j<total; j+=256){
    u32 dw = s_dw[j];
    int typeq = (dw>>20)&1;
    int dst = dw & 0xFFFFF;
    int bg = (typeq?NB:0) + (dst>>8);
    u32 rank = j - (s_scan[bg]-s_cnt[bg]);
    int w0 = (typeq? bg-NB : bg)*256;
    size_t sbase = typeq ? (size_t)TT + (size_t)off_q[w0] : (size_t)off_t[w0];
    stg[sbase + s_gb[bg] + rank] = make_uint2(s_sg[j], dw);
  }
}

// ---------------- T/Q stage B: per-bucket placement ----------------
__global__ __launch_bounds__(256) void k_fillTQ_B(const uint2* __restrict__ stg,
    const int* __restrict__ off_t, const int* __restrict__ off_q,
    u32* __restrict__ csg_t, u32* __restrict__ csg_q){
  __shared__ int curL[256];
  int b = blockIdx.x, t = threadIdx.x;
  int typeq = (b>=NB);
  int bl = typeq? b-NB : b;
  const int* off = typeq? off_q : off_t;
  u32* csg = typeq? csg_q : csg_t;
  int w0 = bl*256, w1 = min(w0+256, NN);
  int s0 = off[w0], s1 = off[w1];
  for (int i=t; i<w1-w0; i+=256) curL[i] = off[w0+i];
  __syncthreads();
  size_t sb = (typeq? (size_t)TT : 0) + (size_t)s0;
  int cnt = s1 - s0;
  for (int i=t; i<cnt; i+=256){
    uint2 r = stg[sb+i];
    int dst = r.y & 0xFFFFF;
    int p = atomicAdd(&curL[dst-w0], 1);
    csg[p] = r.x;
  }
}

// ---------------- GEMM + fused proj: hl16 = fp16(A@W); qa/ka (fp16) for 3 hop types ----------------
#define GR 16
__global__ __launch_bounds__(128) void k_gemm(const float* __restrict__ A, const float* __restrict__ Wm,
    const float* __restrict__ ae, const float* __restrict__ at, const float* __restrict__ aq,
    __half* __restrict__ B16,
    __half* __restrict__ qa_e, __half* __restrict__ ka_e,
    __half* __restrict__ qa_t, __half* __restrict__ ka_t,
    __half* __restrict__ qa_q, __half* __restrict__ ka_q){
  __shared__ float sh[GR][132];
  int col = threadIdx.x;
  int r0 = blockIdx.x * GR;
  const float* Ab = A + (size_t)r0*HID;
  float acc[GR];
  #pragma unroll
  for (int r=0;r<GR;r++) acc[r]=0.f;
  #pragma unroll 4
  for (int k=0;k<HID;k++){
    float wv = Wm[k*HID+col];
    #pragma unroll
    for (int r=0;r<GR;r++) acc[r] = fmaf(Ab[r*HID+k], wv, acc[r]);
  }
  #pragma unroll
  for (int r=0;r<GR;r++){
    B16[(size_t)(r0+r)*HID+col] = __float2half(acc[r]);
    sh[r][col] = acc[r];
  }
  __syncthreads();
  int r = threadIdx.x>>3, h = threadIdx.x&7;
  float x[DH];
  #pragma unroll
  for (int j=0;j<DH;j++) x[j] = sh[r][h*DH+j];
  const float* Ae = ae + h*33; const float* At_ = at + h*33; const float* Aq = aq + h*33;
  float s0=0,s1=0,s2=0,s3=0,s4=0,s5=0;
  #pragma unroll
  for (int d=0; d<DH; d++){
    s0 = fmaf(x[d], Ae[d],      s0);  s1 = fmaf(x[d], Ae[DH+d],  s1);
    s2 = fmaf(x[d], At_[d],     s2);  s3 = fmaf(x[d], At_[DH+d], s3);
    s4 = fmaf(x[d], Aq[d],      s4);  s5 = fmaf(x[d], Aq[DH+d],  s5);
  }
  size_t o = (size_t)(r0+r)*NH + h;
  qa_e[o]=__float2half(s0); ka_e[o]=__float2half(s1);
  qa_t[o]=__float2half(s2); ka_t[o]=__float2half(s3);
  qa_q[o]=__float2half(s4); ka_q[o]=__float2half(s5);
}

// ---------------- fused 3-hop attention; wave-per-node, unified logit phase,
// 4-rows/iter 16B-load gather ----------------
__global__ __launch_bounds__(256) void k_hop3(
    const int* __restrict__ off_e, const int* __restrict__ off_t, const int* __restrict__ off_q,
    const u32* __restrict__ eRec,
    const u32* __restrict__ csg_t, const u32* __restrict__ csg_q,
    const __half* __restrict__ qa_e, const __half* __restrict__ ka_e,
    const __half* __restrict__ qa_t, const __half* __restrict__ ka_t,
    const __half* __restrict__ qa_q, const __half* __restrict__ ka_q,
    const float* __restrict__ ae, const float* __restrict__ at, const float* __restrict__ aq,
    const __half* __restrict__ hh16, const __half* __restrict__ hlr16, float* __restrict__ hout,
    int L, int nwaves){
  __shared__ u32 sw[4][3*CAP*SLOT];   // 15360 B: packed fp16 alpha x4 + src per edge
  int t = threadIdx.x;
  int wv = t>>6, l = t&63;
  u32* Wb = sw[wv];
  // gather decomposition: lane group lg handles rows m+lg; ld covers dims ld*8..ld*8+7
  int lg = l>>4, ld = l&15;
  int wiR = ld>>2;                 // u32 word holding my head's alpha
  int shR = ((ld>>1)&1)*16;        // hi/lo half
  // per-head geometry coefficients: uniform -> scalar loads
  float cfE[8], cfT[8], cfQ[8];
  #pragma unroll
  for (int h=0;h<8;h++){ cfE[h]=ae[h*33+32]; cfT[h]=at[h*33+32]; cfQ[h]=aq[h*33+32]; }
  for (int n = blockIdx.x*4 + wv; n < NN; n += nwaves){
    int se=off_e[n], de=off_e[n+1]-se;
    int st=off_t[n], dt=off_t[n+1]-st;
    int sq=off_q[n], dq=off_q[n+1]-sq;
    float accE[8]={0,0,0,0,0,0,0,0}, accT[8]={0,0,0,0,0,0,0,0}, accQ[8]={0,0,0,0,0,0,0,0};
    float dE=0.f, dT=0.f, dQ=0.f;
    int maxd = max(de, max(dt, dq));
    for (int base=0; base<maxd; base+=CAP){
      int ce = min(CAP, de-base); if (ce<0) ce=0;
      int ct = min(CAP, dt-base); if (ct<0) ct=0;
      int cq = min(CAP, dq-base); if (cq<0) cq=0;
      // ---- unified logit phase: all three hops' loads in flight ----
      if (l < ce){
        size_t idx = (size_t)(se+base+l);
        u32 sg = eRec[idx*16];
        u32x4 br = *(const u32x4*)(eRec + idx*16 + 4 + 4*L);
        int src = (int)(sg>>16);
        float g = lo16(sg);
        float ka8[8]; unpack8(ka_e + (size_t)src*NH, ka8);
        float qa8[8]; unpack8(qa_e + (size_t)n*NH, qa8);
        u32* sl = Wb + l*SLOT;
        #pragma unroll
        for (int j=0;j<4;j++){
          u32 bw = br[j];
          float l0 = qa8[2*j]   + ka8[2*j]   + g*cfE[2*j]   + lo16(bw);
          float l1 = qa8[2*j+1] + ka8[2*j+1] + g*cfE[2*j+1] + hi16(bw);
          l0 = l0>=0.f ? l0 : 0.2f*l0;
          l1 = l1>=0.f ? l1 : 0.2f*l1;
          sl[j] = packf2(__expf(l0), __expf(l1));
        }
        sl[4] = (u32)src;
      }
      if (l < ct){
        u32 sg = csg_t[(size_t)(st+base+l)];
        int src = (int)(sg>>16);
        float g = lo16(sg);
        float ka8[8]; unpack8(ka_t + (size_t)src*NH, ka8);
        float qa8[8]; unpack8(qa_t + (size_t)n*NH, qa8);
        u32* sl = Wb + CAP*SLOT + l*SLOT;
        #pragma unroll
        for (int j=0;j<4;j++){
          float l0 = qa8[2*j]   + ka8[2*j]   + g*cfT[2*j];
          float l1 = qa8[2*j+1] + ka8[2*j+1] + g*cfT[2*j+1];
          l0 = l0>=0.f ? l0 : 0.2f*l0;
          l1 = l1>=0.f ? l1 : 0.2f*l1;
          sl[j] = packf2(__expf(l0), __expf(l1));
        }
        sl[4] = (u32)src;
      }
      if (l < cq){
        u32 sg = csg_q[(size_t)(sq+base+l)];
        int src = (int)(sg>>16);
        float g = lo16(sg);
        float ka8[8]; unpack8(ka_q + (size_t)src*NH, ka8);
        float qa8[8]; unpack8(qa_q + (size_t)n*NH, qa8);
        u32* sl = Wb + 2*CAP*SLOT + l*SLOT;
        #pragma unroll
        for (int j=0;j<4;j++){
          float l0 = qa8[2*j]   + ka8[2*j]   + g*cfQ[2*j];
          float l1 = qa8[2*j+1] + ka8[2*j+1] + g*cfQ[2*j+1];
          l0 = l0>=0.f ? l0 : 0.2f*l0;
          l1 = l1>=0.f ? l1 : 0.2f*l1;
          sl[j] = packf2(__expf(l0), __expf(l1));
        }
        sl[4] = (u32)src;
      }
      __builtin_amdgcn_wave_barrier();
      // ---- gather: 4 rows/iteration, 16B loads per lane ----
      {
        const u32* P = Wb;
        #pragma unroll 2
        for (int m=0;m<ce;m+=4){
          int r = m+lg;
          int rr = min(r, ce-1);
          u32 aw = P[rr*SLOT+wiR];
          u32 sr = P[rr*SLOT+4];
          float am = (r<ce)? __half2float(__ushort_as_half((unsigned short)(aw>>shR))) : 0.f;
          u32x4 v = *(const u32x4*)(hh16 + (size_t)sr*HID + ld*8);
          dE += am;
          #pragma unroll
          for (int j=0;j<4;j++){
            u32 w = v[j];
            accE[2*j]   = fmaf(lo16(w), am, accE[2*j]);
            accE[2*j+1] = fmaf(hi16(w), am, accE[2*j+1]);
          }
        }
      }
      {
        const u32* P = Wb + CAP*SLOT;
        #pragma unroll 2
        for (int m=0;m<ct;m+=4){
          int r = m+lg;
          int rr = min(r, ct-1);
          u32 aw = P[rr*SLOT+wiR];
          u32 sr = P[rr*SLOT+4];
          float am = (r<ct)? __half2float(__ushort_as_half((unsigned short)(aw>>shR))) : 0.f;
          u32x4 v = *(const u32x4*)(hh16 + (size_t)sr*HID + ld*8);
          dT += am;
          #pragma unroll
          for (int j=0;j<4;j++){
            u32 w = v[j];
            accT[2*j]   = fmaf(lo16(w), am, accT[2*j]);
            accT[2*j+1] = fmaf(hi16(w), am, accT[2*j+1]);
          }
        }
      }
      {
        const u32* P = Wb + 2*CAP*SLOT;
        #pragma unroll 2
        for (int m=0;m<cq;m+=4){
          int r = m+lg;
          int rr = min(r, cq-1);
          u32 aw = P[rr*SLOT+wiR];
          u32 sr = P[rr*SLOT+4];
          float am = (r<cq)? __half2float(__ushort_as_half((unsigned short)(aw>>shR))) : 0.f;
          u32x4 v = *(const u32x4*)(hh16 + (size_t)sr*HID + ld*8);
          dQ += am;
          #pragma unroll
          for (int j=0;j<4;j++){
            u32 w = v[j];
            accQ[2*j]   = fmaf(lo16(w), am, accQ[2*j]);
            accQ[2*j+1] = fmaf(hi16(w), am, accQ[2*j+1]);
          }
        }
      }
      __builtin_amdgcn_wave_barrier();
    }
    // ---- cross-lane-group reduce (lanes l, l+16, l+32, l+48 share (ld -> dims/head)) ----
    #pragma unroll
    for (int j=0;j<8;j++){
      accE[j] += __shfl_xor(accE[j],16); accE[j] += __shfl_xor(accE[j],32);
      accT[j] += __shfl_xor(accT[j],16); accT[j] += __shfl_xor(accT[j],32);
      accQ[j] += __shfl_xor(accQ[j],16); accQ[j] += __shfl_xor(accQ[j],32);
    }
    dE += __shfl_xor(dE,16); dE += __shfl_xor(dE,32);
    dT += __shfl_xor(dT,16); dT += __shfl_xor(dT,32);
    dQ += __shfl_xor(dQ,16); dQ += __shfl_xor(dQ,32);
    if (lg == 0){
      float invE = 1.f/(dE + 1e-16f);
      float invT = 1.f/(dT + 1e-16f);
      float invQ = 1.f/(dQ + 1e-16f);
      float ov[8];
      #pragma unroll
      for (int j=0;j<8;j++) ov[j] = accE[j]*invE + accT[j]*invT + accQ[j]*invQ;
      size_t oi = (size_t)n*HID + ld*8;
      u32x4 rv = *(const u32x4*)(hlr16 + oi);
      float r8[8];
      #pragma unroll
      for (int j=0;j<4;j++){ u32 w=rv[j]; r8[2*j]=lo16(w); r8[2*j+1]=hi16(w); }
      float4 w0 = make_float4(eluf(r8[0]+ov[0]), eluf(r8[1]+ov[1]), eluf(r8[2]+ov[2]), eluf(r8[3]+ov[3]));
      float4 w1 = make_float4(eluf(r8[4]+ov[4]), eluf(r8[5]+ov[5]), eluf(r8[6]+ov[6]), eluf(r8[7]+ov[7]));
      *(float4*)(hout+oi)   = w0;
      *(float4*)(hout+oi+4) = w1;
    }
  }
}

// ---------------- pooling: sum + max per graph ----------------
__global__ __launch_bounds__(128) void k_pool(const float* __restrict__ h, const int* __restrict__ goff,
                                              float* __restrict__ gs, float* __restrict__ gmx){
  int g = blockIdx.x, t = threadIdx.x;
  int s = goff[g], e = goff[g+1];
  float sum = 0.f, mx = -INFINITY;
  for (int n=s; n<e; n++){
    float v = h[(size_t)n*HID+t];
    sum += v; mx = fmaxf(mx, v);
  }
  gs[(size_t)g*HID+t] = sum;
  gmx[(size_t)g*HID+t] = (s < e) ? mx : 0.f;
}

// ---------------- readout MLP: [257]->256->256->1, 8 graphs per block ----------------
#define GPB 8
#define MSTR 260
__global__ __launch_bounds__(256) void k_mlp(const float* __restrict__ gs, const float* __restrict__ gmx,
    const float* __restrict__ temps,
    const float* __restrict__ W1, const float* __restrict__ b1,
    const float* __restrict__ W2, const float* __restrict__ b2,
    const float* __restrict__ W3, const float* __restrict__ b3,
    float* __restrict__ out){
  __shared__ float mol[GPB][MSTR];
  __shared__ float hd[GPB][MSTR];
  int g0 = blockIdx.x*GPB, t = threadIdx.x;
  for (int i=t; i<GPB*HID; i+=256){
    int g=i>>7, d=i&127;
    mol[g][d]     = gs[(size_t)(g0+g)*HID+d];
    mol[g][128+d] = gmx[(size_t)(g0+g)*HID+d];
  }
  if (t < GPB){ mol[t][256]=temps[g0+t]; mol[t][257]=0.f; mol[t][258]=0.f; mol[t][259]=0.f; }
  __syncthreads();
  float acc[GPB];
  #pragma unroll
  for (int g=0;g<GPB;g++) acc[g]=b1[t];
  for (int k0=0;k0<256;k0+=4){
    float w0=W1[(size_t)(k0+0)*256+t], w1=W1[(size_t)(k0+1)*256+t];
    float w2=W1[(size_t)(k0+2)*256+t], w3=W1[(size_t)(k0+3)*256+t];
    #pragma unroll
    for (int g=0;g<GPB;g++){
      float4 m4 = *(const float4*)&mol[g][k0];
      acc[g] = fmaf(m4.x,w0, fmaf(m4.y,w1, fmaf(m4.z,w2, fmaf(m4.w,w3, acc[g]))));
    }
  }
  { float wl=W1[(size_t)256*256+t];
    #pragma unroll
    for (int g=0;g<GPB;g++) acc[g]=fmaf(mol[g][256],wl,acc[g]); }
  #pragma unroll
  for (int g=0;g<GPB;g++) hd[g][t]=eluf(acc[g]);
  __syncthreads();
  #pragma unroll
  for (int g=0;g<GPB;g++) acc[g]=b2[t];
  for (int k0=0;k0<256;k0+=4){
    float w0=W2[(size_t)(k0+0)*256+t], w1=W2[(size_t)(k0+1)*256+t];
    float w2=W2[(size_t)(k0+2)*256+t], w3=W2[(size_t)(k0+3)*256+t];
    #pragma unroll
    for (int g=0;g<GPB;g++){
      float4 h4 = *(const float4*)&hd[g][k0];
      acc[g] = fmaf(h4.x,w0, fmaf(h4.y,w1, fmaf(h4.z,w2, fmaf(h4.w,w3, acc[g]))));
    }
  }
  float w3v = W3[t];
  #pragma unroll
  for (int g=0;g<GPB;g++) mol[g][t] = eluf(acc[g])*w3v;
  __syncthreads();
  int g = t >> 5, j = t & 31;
  float s = 0.f;
  for (int i=j; i<256; i+=32) s += mol[g][i];
  #pragma unroll
  for (int d=16; d>0; d>>=1) s += __shfl_down(s, d, 32);
  if (j == 0) out[g0+g] = s + b3[0];
}

extern "C" void kernel_launch(void* const* d_in, const int* in_sizes, int n_in,
                              void* d_out, int out_size, void* d_ws, size_t ws_size,
                              hipStream_t stream){
  const float* x         = (const float*)d_in[0];
  const float* pos       = (const float*)d_in[1];
  const float* edge_attr = (const float*)d_in[2];
  const float* temps     = (const float*)d_in[3];
  const int*   ei        = (const int*)d_in[4];
  const int*   ti        = (const int*)d_in[5];
  const int*   qi        = (const int*)d_in[6];
  const int*   batch     = (const int*)d_in[7];
  const float* W         = (const float*)d_in[8];
  const float* a_e       = (const float*)d_in[9];
  const float* a_t       = (const float*)d_in[10];
  const float* a_q       = (const float*)d_in[11];
  const float* We        = (const float*)d_in[12];
  const float* W1        = (const float*)d_in[13];
  const float* b1        = (const float*)d_in[14];
  const float* W2        = (const float*)d_in[15];
  const float* b2        = (const float*)d_in[16];
  const float* W3        = (const float*)d_in[17];
  const float* b3        = (const float*)d_in[18];
  float* out = (float*)d_out;

  char* base = (char*)d_ws; size_t woff = 0;
  auto alloc = [&](size_t bytes)->void*{
    void* p = base + woff;
    woff = (woff + bytes + 255) & ~(size_t)255;
    return p;
  };
  float*  hbuf   = (float*)alloc((size_t)NN*HID*4);
  __half* hl16   = (__half*)alloc((size_t)NN*HID*2);
  __half* qa_e   = (__half*)alloc((size_t)NN*NH*2);
  __half* ka_e   = (__half*)alloc((size_t)NN*NH*2);
  __half* qa_t   = (__half*)alloc((size_t)NN*NH*2);
  __half* ka_t   = (__half*)alloc((size_t)NN*NH*2);
  __half* qa_q   = (__half*)alloc((size_t)NN*NH*2);
  __half* ka_q   = (__half*)alloc((size_t)NN*NH*2);
  u32*    eRec   = (u32*)alloc((size_t)EE*64);
  u32*    csg_t  = (u32*)alloc((size_t)TT*4);
  u32*    csg_q  = (u32*)alloc((size_t)QQ*4);
  uint2*  stg    = (uint2*)alloc((size_t)(TT+QQ)*8);
  float*  gs     = (float*)alloc((size_t)GG*HID*4);
  float*  gmx    = (float*)alloc((size_t)GG*HID*4);
  int*    cnt    = (int*)alloc((size_t)3*NN*4);
  u32*    gcur   = (u32*)alloc((size_t)NBG*4);
  int*    off_e  = (int*)alloc((size_t)(NN+1)*4);
  int*    off_t  = (int*)alloc((size_t)(NN+1)*4);
  int*    off_q  = (int*)alloc((size_t)(NN+1)*4);
  int*    cur_e  = (int*)alloc((size_t)NN*4);
  int*    cur_t  = (int*)alloc((size_t)NN*4);
  int*    cur_q  = (int*)alloc((size_t)NN*4);
  int*    goff   = (int*)alloc((size_t)(GG+1)*4);

  // ---- CSR build + geometry ----
  hipMemsetAsync(cnt, 0, (size_t)3*NN*4, stream);
  hipMemsetAsync(gcur, 0, (size_t)NBG*4, stream);
  int tot = EE+TT+QQ;
  k_count3<<<(tot+255)/256,256,0,stream>>>(ei, ti, qi, cnt);
  k_scan4<<<4,1024,0,stream>>>(cnt, off_e, off_t, off_q, cur_e, cur_t, cur_q, batch, goff);
  k_fillE<<<(EE+255)/256,256,0,stream>>>(pos, edge_attr, ei, We, cur_e, eRec);
  k_fillTQ_A<<<(TT+QQ+TILE-1)/TILE,256,0,stream>>>(pos, ti, qi, off_t, off_q, gcur, stg);
  k_fillTQ_B<<<NBG,256,0,stream>>>(stg, off_t, off_q, csg_t, csg_q);

  // ---- layers ----
  int hopBlocks = 2048;
  int nwaves = hopBlocks*4;
  for (int l=0; l<3; l++){
    const float* hin = (l==0) ? x : hbuf;
    k_gemm<<<NN/GR,128,0,stream>>>(hin, W + (size_t)l*HID*HID,
                                   a_e+l*264, a_t+l*264, a_q+l*264,
                                   hl16, qa_e, ka_e, qa_t, ka_t, qa_q, ka_q);
    k_hop3<<<hopBlocks,256,0,stream>>>(off_e, off_t, off_q, eRec, csg_t, csg_q,
                                       qa_e, ka_e, qa_t, ka_t, qa_q, ka_q,
                                       a_e+l*264, a_t+l*264, a_q+l*264,
                                       hl16, hl16, hbuf, l, nwaves);
  }

  // ---- readout ----
  k_pool<<<GG,128,0,stream>>>(hbuf, goff, gs, gmx);
  k_mlp<<<GG/GPB,256,0,stream>>>(gs, gmx, temps, W1, b1, W2, b2, W3, b3, out);
}